// Round 9
// baseline (435.158 us; speedup 1.0000x reference)
//
#include <hip/hip_runtime.h>
#include <hip/hip_fp16.h>
#include <cstdint>
#include <cstddef>

// ---------------------------------------------------------------------------
// GAT x2 + LayerNorm on MI355X.
// R16: counting-sort CSR + overlay fix (verified 434us).
// R19: scores fused into gemm1 epilogue + aggregate1 epilogue (verified 408us).
// R20 (this round): wide-gather restructure.
//   - aggregate1/agg2in: 16B/lane bf16x8 gathers, wave split into two 32-lane
//     halves processing 2 edges per VMEM instruction (halves VMEM instr count,
//     doubles bytes per vmcnt entry; same bytes, same FLOPs).
//   - alpha: 16 lanes/node (4 nodes/wave) — avg degree 17 left 73% lanes idle.
// ---------------------------------------------------------------------------

constexpr int NNODES = 50000;
constexpr int NBINS = (NNODES + 255) >> 8;   // 196 coarse bins (256 nodes each)
constexpr int ABLOCKS = 256;                 // binning grid

typedef unsigned short bf16_t;
typedef __attribute__((ext_vector_type(8))) short bf16x8;
typedef __attribute__((ext_vector_type(4))) float f32x4;

__device__ __forceinline__ float bf2f(bf16_t b) {
  return __uint_as_float(((unsigned int)b) << 16);
}
__device__ __forceinline__ bf16_t f2bf(float f) {
  unsigned int u = __float_as_uint(f);
  u += 0x7fffu + ((u >> 16) & 1u);   // round to nearest even
  return (bf16_t)(u >> 16);
}
__device__ __forceinline__ float4 bf4_to_f4(ushort4 v) {
  return make_float4(bf2f(v.x), bf2f(v.y), bf2f(v.z), bf2f(v.w));
}
__device__ __forceinline__ ushort4 f4_to_bf4(float4 v) {
  return make_ushort4(f2bf(v.x), f2bf(v.y), f2bf(v.z), f2bf(v.w));
}
__device__ __forceinline__ ushort f2h(float f) {
  __half h = __float2half_rn(f);
  return *(ushort*)&h;
}
__device__ __forceinline__ float h2f(ushort u) {
  __half h; *(ushort*)&h = u;
  return __half2float(h);
}
__device__ __forceinline__ float lrelu(float x) { return x > 0.f ? x : 0.2f * x; }
__device__ __forceinline__ int clampi(int v, int lo, int hi) {
  return v < lo ? lo : (v > hi ? hi : v);
}
__device__ __forceinline__ int load_edge(const void* ei, int mode, int idx) {
  if (mode) return (int)((const long long*)ei)[idx];
  return ((const int*)ei)[idx];
}

// ------------------------------ prep kernels -------------------------------

__global__ void convert_x_kernel(const float* __restrict__ x, bf16_t* __restrict__ xb,
                                 int n4) {
  int i = blockIdx.x * blockDim.x + threadIdx.x;
  if (i >= n4) return;
  float4 v = *(const float4*)(x + 4 * (size_t)i);
  *(ushort4*)(xb + 4 * (size_t)i) = f4_to_bf4(v);
}

template <int K, int NC>
__global__ void transpose_w_kernel(const float* __restrict__ W, bf16_t* __restrict__ Wt) {
  int n = blockIdx.x;
  int k = threadIdx.x;
  Wt[(size_t)n * K + k] = f2bf(W[(size_t)k * NC + n]);
}

// ws2[h,k] = sum_c W2[k, h*128+c] * a_src2[h,c]   (and wd2 with a_dst2)
__global__ void proj2_kernel(const float* __restrict__ W2,
                             const float* __restrict__ asrc2,
                             const float* __restrict__ adst2,
                             float* __restrict__ ws2, float* __restrict__ wd2) {
  int h = blockIdx.x;      // 0..3
  int k = threadIdx.x;     // 0..255
  const float* wrow = W2 + (size_t)k * 512 + h * 128;
  const float* as = asrc2 + h * 128;
  const float* ad = adst2 + h * 128;
  float s = 0.f, d = 0.f;
  for (int c = 0; c < 128; ++c) { s += wrow[c] * as[c]; d += wrow[c] * ad[c]; }
  ws2[h * 256 + k] = s;
  wd2[h * 256 + k] = d;
}

// Wt2s[c][h*256+k] = W2[k, h*128+c] * 0.25  (stacked weight, transposed, bf16)
__global__ __launch_bounds__(1024) void wstack_kernel(const float* __restrict__ W2,
                                                      bf16_t* __restrict__ Wt2s) {
  int c = blockIdx.x;      // 0..127
  int t = threadIdx.x;     // 0..1023 : h = t>>8, k = t&255
  int h = t >> 8, k = t & 255;
  Wt2s[(size_t)c * 1024 + t] = f2bf(W2[(size_t)k * 512 + h * 128 + c] * 0.25f);
}

// --------------------------- edge dtype detection --------------------------
__global__ void detect_kernel(const int* __restrict__ ei32, int* __restrict__ mode) {
  __shared__ int nz;
  if (threadIdx.x == 0) nz = 0;
  __syncthreads();
  int idx = 2 * threadIdx.x + 1;
  if (ei32[idx] != 0) atomicAdd(&nz, 1);
  __syncthreads();
  if (threadIdx.x == 0) mode[0] = (nz == 0) ? 1 : 0;
}

// --------------------- CSR build: two-level counting sort ------------------
__global__ __launch_bounds__(256) void binhist_kernel(
    const void* __restrict__ ei, const int* __restrict__ modep,
    int* __restrict__ blockBin, int e0, int et, int chunk) {
  __shared__ int h[NBINS];
  int t = threadIdx.x, blk = blockIdx.x;
  for (int i = t; i < NBINS; i += 256) h[i] = 0;
  __syncthreads();
  int mode = modep[0];
  int lo = blk * chunk, hi = min(et, lo + chunk);
  for (int e = lo + t; e < hi; e += 256) {
    int dst = (e < e0) ? load_edge(ei, mode, e0 + e) : (e - e0);
    dst = clampi(dst, 0, NNODES - 1);
    atomicAdd(&h[dst >> 8], 1);
  }
  __syncthreads();
  for (int i = t; i < NBINS; i += 256) blockBin[i * ABLOCKS + blk] = h[i];
}

__global__ __launch_bounds__(ABLOCKS) void binscanA_kernel(int* __restrict__ blockBin,
                                                           int* __restrict__ binTotal) {
  __shared__ int sm[ABLOCKS];
  int b = blockIdx.x, t = threadIdx.x;
  int orig = blockBin[b * ABLOCKS + t];
  sm[t] = orig;
  __syncthreads();
  for (int off = 1; off < ABLOCKS; off <<= 1) {
    int u = (t >= off) ? sm[t - off] : 0;
    __syncthreads();
    sm[t] += u;
    __syncthreads();
  }
  blockBin[b * ABLOCKS + t] = sm[t] - orig;
  if (t == ABLOCKS - 1) binTotal[b] = sm[ABLOCKS - 1];
}

__global__ __launch_bounds__(256) void binscanB_kernel(const int* __restrict__ binTotal,
                                                       int* __restrict__ binStart) {
  __shared__ int sm[256];
  int t = threadIdx.x;
  int orig = (t < NBINS) ? binTotal[t] : 0;
  sm[t] = orig;
  __syncthreads();
  for (int off = 1; off < 256; off <<= 1) {
    int u = (t >= off) ? sm[t - off] : 0;
    __syncthreads();
    sm[t] += u;
    __syncthreads();
  }
  if (t < NBINS) binStart[t] = sm[t] - orig;
  if (t == 255) binStart[NBINS] = sm[255];
}

__global__ __launch_bounds__(256) void binscatter_kernel(
    const void* __restrict__ ei, const int* __restrict__ modep,
    const int* __restrict__ blockBin, const int* __restrict__ binStart,
    int2* __restrict__ pairs, int e0, int et, int chunk) {
  __shared__ int cur[NBINS];
  int t = threadIdx.x, blk = blockIdx.x;
  for (int i = t; i < NBINS; i += 256)
    cur[i] = binStart[i] + blockBin[i * ABLOCKS + blk];
  __syncthreads();
  int mode = modep[0];
  int lo = blk * chunk, hi = min(et, lo + chunk);
  for (int e = lo + t; e < hi; e += 256) {
    int src, dst;
    if (e < e0) { src = load_edge(ei, mode, e); dst = load_edge(ei, mode, e0 + e); }
    else        { src = dst = e - e0; }
    src = clampi(src, 0, NNODES - 1);
    dst = clampi(dst, 0, NNODES - 1);
    int p = atomicAdd(&cur[dst >> 8], 1);
    pairs[p] = make_int2(src, dst);
  }
}

// B: per-bin CSR finalize — defensive clamp keeps LDS safe.
__global__ __launch_bounds__(256) void csrbin_kernel(const int2* __restrict__ pairs,
                                                     const int* __restrict__ binStart,
                                                     int* __restrict__ rowptr,
                                                     int* __restrict__ col) {
  __shared__ int cnt[256];
  __shared__ int sc[256];
  int b = blockIdx.x, t = threadIdx.x;
  int node0 = b << 8;
  int es = binStart[b], ee = binStart[b + 1];
  cnt[t] = 0;
  __syncthreads();
  for (int p = es + t; p < ee; p += 256) {
    int2 pr = pairs[p];
    int d = clampi(pr.y - node0, 0, 255);
    atomicAdd(&cnt[d], 1);
  }
  __syncthreads();
  int orig = cnt[t];
  sc[t] = orig;
  __syncthreads();
  for (int off = 1; off < 256; off <<= 1) {
    int u = (t >= off) ? sc[t - off] : 0;
    __syncthreads();
    sc[t] += u;
    __syncthreads();
  }
  int excl = sc[t] - orig;
  if (node0 + t < NNODES) rowptr[node0 + t] = es + excl;
  if (b == NBINS - 1 && t == 0) rowptr[NNODES] = ee;
  cnt[t] = excl;
  __syncthreads();
  for (int p = es + t; p < ee; p += 256) {
    int2 pr = pairs[p];
    int d = clampi(pr.y - node0, 0, 255);
    int pos = atomicAdd(&cnt[d], 1);
    col[es + pos] = pr.x;
  }
}

// --------------- MFMA GEMM (layer 1) with fused layer-1 scores -------------
__global__ __launch_bounds__(256) void gemm1s_kernel(
    const bf16_t* __restrict__ A, const bf16_t* __restrict__ Wt,
    bf16_t* __restrict__ C, const float* __restrict__ asrc,
    const float* __restrict__ adst, float* __restrict__ es,
    float* __restrict__ ed, int M) {
  __shared__ __align__(16) ushort As[64 * 40];
  __shared__ __align__(16) ushort Bs[64 * 40];
  const int t    = threadIdx.x;
  const int wv   = t >> 6;
  const int lane = t & 63;
  const int m    = lane & 15;
  const int quad = lane >> 4;
  const int bm = blockIdx.x * 64, bn = blockIdx.y * 64;
  const int srow = t & 63;
  const int sk8  = t >> 6;

  f32x4 acc0 = {0.f, 0.f, 0.f, 0.f};
  f32x4 acc1 = {0.f, 0.f, 0.f, 0.f};
  f32x4 acc2 = {0.f, 0.f, 0.f, 0.f};
  f32x4 acc3 = {0.f, 0.f, 0.f, 0.f};

  for (int k0 = 0; k0 < 128; k0 += 32) {
    int ga = clampi(bm + srow, 0, M - 1);
    float4 av = *(const float4*)(A + (size_t)ga * 128 + k0 + sk8 * 8);
    *(float4*)(&As[srow * 40 + sk8 * 8]) = av;
    float4 bv = *(const float4*)(Wt + (size_t)(bn + srow) * 128 + k0 + sk8 * 8);
    *(float4*)(&Bs[srow * 40 + sk8 * 8]) = bv;
    __syncthreads();

    bf16x8 af = *(const bf16x8*)(&As[(wv * 16 + m) * 40 + quad * 8]);
    bf16x8 b0 = *(const bf16x8*)(&Bs[(0 * 16 + m) * 40 + quad * 8]);
    bf16x8 b1 = *(const bf16x8*)(&Bs[(1 * 16 + m) * 40 + quad * 8]);
    bf16x8 b2 = *(const bf16x8*)(&Bs[(2 * 16 + m) * 40 + quad * 8]);
    bf16x8 b3 = *(const bf16x8*)(&Bs[(3 * 16 + m) * 40 + quad * 8]);
    acc0 = __builtin_amdgcn_mfma_f32_16x16x32_bf16(af, b0, acc0, 0, 0, 0);
    acc1 = __builtin_amdgcn_mfma_f32_16x16x32_bf16(af, b1, acc1, 0, 0, 0);
    acc2 = __builtin_amdgcn_mfma_f32_16x16x32_bf16(af, b2, acc2, 0, 0, 0);
    acc3 = __builtin_amdgcn_mfma_f32_16x16x32_bf16(af, b3, acc3, 0, 0, 0);
    __syncthreads();
  }

  float as0 = asrc[bn +  0 + m], as1 = asrc[bn + 16 + m];
  float as2 = asrc[bn + 32 + m], as3 = asrc[bn + 48 + m];
  float ad0 = adst[bn +  0 + m], ad1 = adst[bn + 16 + m];
  float ad2 = adst[bn + 32 + m], ad3 = adst[bn + 48 + m];
  const int hd = bn >> 6;

#pragma unroll
  for (int r = 0; r < 4; ++r) {
    int row = bm + wv * 16 + quad * 4 + r;
    float ps = acc0[r] * as0 + acc1[r] * as1 + acc2[r] * as2 + acc3[r] * as3;
    float pd = acc0[r] * ad0 + acc1[r] * ad1 + acc2[r] * ad2 + acc3[r] * ad3;
    for (int mm = 1; mm < 16; mm <<= 1) {
      ps += __shfl_xor(ps, mm);
      pd += __shfl_xor(pd, mm);
    }
    if (row < M) {
      size_t base = (size_t)row * 256 + bn;
      C[base +  0 + m] = f2bf(acc0[r]);
      C[base + 16 + m] = f2bf(acc1[r]);
      C[base + 32 + m] = f2bf(acc2[r]);
      C[base + 48 + m] = f2bf(acc3[r]);
      if (m == 0) {
        es[row * 4 + hd] = ps;
        ed[row * 4 + hd] = pd;
      }
    }
  }
}

// --------------------------- alpha precompute (fp16) -----------------------
// R20: 16 lanes per node (4 nodes/wave) — avg degree ~17 left 73% lanes idle
// in the 64-lane version.
__global__ __launch_bounds__(256) void alpha_kernel(
    const float* __restrict__ es, const float* __restrict__ ed,
    const int* __restrict__ rowptr, const int* __restrict__ col,
    ushort* __restrict__ alpha) {
  int node = (blockIdx.x * blockDim.x + threadIdx.x) >> 4;
  if (node >= NNODES) return;
  int l16 = threadIdx.x & 15;
  int beg = rowptr[node], end = rowptr[node + 1];
  float4 edv = *(const float4*)(ed + node * 4);
  float4 l = make_float4(0.f, 0.f, 0.f, 0.f);
  for (int p = beg + l16; p < end; p += 16) {
    int s = col[p];
    float4 e = *(const float4*)(es + s * 4);
    l.x += __expf(lrelu(e.x + edv.x));
    l.y += __expf(lrelu(e.y + edv.y));
    l.z += __expf(lrelu(e.z + edv.z));
    l.w += __expf(lrelu(e.w + edv.w));
  }
  for (int off = 1; off < 16; off <<= 1) {
    l.x += __shfl_xor(l.x, off);
    l.y += __shfl_xor(l.y, off);
    l.z += __shfl_xor(l.z, off);
    l.w += __shfl_xor(l.w, off);
  }
  float4 il = make_float4(1.f / (l.x + 1e-16f), 1.f / (l.y + 1e-16f),
                          1.f / (l.z + 1e-16f), 1.f / (l.w + 1e-16f));
  for (int p = beg + l16; p < end; p += 16) {
    int s = col[p];
    float4 e = *(const float4*)(es + s * 4);
    ushort4 a;
    a.x = f2h(__expf(lrelu(e.x + edv.x)) * il.x);
    a.y = f2h(__expf(lrelu(e.y + edv.y)) * il.y);
    a.z = f2h(__expf(lrelu(e.z + edv.z)) * il.z);
    a.w = f2h(__expf(lrelu(e.w + edv.w)) * il.w);
    *(ushort4*)(alpha + (size_t)p * 4) = a;
  }
}

// ------------------------------- aggregation -------------------------------
// layer 1 (R20 wide-gather): wave per node split into two 32-lane halves;
// half processes edge j+half; lane covers channels [8cl, 8cl+8) via one
// 16B bf16x8 load. Combine halves with shfl_xor(,32). Fused layer-2 scores.
__global__ __launch_bounds__(256) void aggregate1_kernel(
    const bf16_t* __restrict__ h, const ushort* __restrict__ alpha,
    const int* __restrict__ rowptr, const int* __restrict__ col,
    const float* __restrict__ b1, bf16_t* __restrict__ out,
    const float* __restrict__ ws2, const float* __restrict__ wd2,
    float* __restrict__ es2, float* __restrict__ ed2) {
  int node = (blockIdx.x * blockDim.x + threadIdx.x) >> 6;
  if (node >= NNODES) return;
  int lane = threadIdx.x & 63;
  int half = lane >> 5;
  int cl   = lane & 31;          // channels [8cl, 8cl+8)
  int head = cl >> 3;
  int beg = rowptr[node], end = rowptr[node + 1];
  float acc[8] = {0.f, 0.f, 0.f, 0.f, 0.f, 0.f, 0.f, 0.f};
  int j = beg;
  for (; j + 2 <= end; j += 2) {
    int e = j + half;
    int s = col[e];
    float a = h2f(alpha[(size_t)e * 4 + head]);
    bf16x8 r = *(const bf16x8*)(h + (size_t)s * 256 + 8 * cl);
#pragma unroll
    for (int i = 0; i < 8; ++i) acc[i] += a * bf2f((ushort)r[i]);
  }
  if (j < end && half == 0) {
    int s = col[j];
    float a = h2f(alpha[(size_t)j * 4 + head]);
    bf16x8 r = *(const bf16x8*)(h + (size_t)s * 256 + 8 * cl);
#pragma unroll
    for (int i = 0; i < 8; ++i) acc[i] += a * bf2f((ushort)r[i]);
  }
#pragma unroll
  for (int i = 0; i < 8; ++i) acc[i] += __shfl_xor(acc[i], 32);

  float4 bA = *(const float4*)(b1 + 8 * cl);
  float4 bB = *(const float4*)(b1 + 8 * cl + 4);
  float o[8];
  o[0] = fmaxf(acc[0] + bA.x, 0.f);  o[1] = fmaxf(acc[1] + bA.y, 0.f);
  o[2] = fmaxf(acc[2] + bA.z, 0.f);  o[3] = fmaxf(acc[3] + bA.w, 0.f);
  o[4] = fmaxf(acc[4] + bB.x, 0.f);  o[5] = fmaxf(acc[5] + bB.y, 0.f);
  o[6] = fmaxf(acc[6] + bB.z, 0.f);  o[7] = fmaxf(acc[7] + bB.w, 0.f);
  if (half == 0) {
    bf16x8 ov;
#pragma unroll
    for (int i = 0; i < 8; ++i) ov[i] = (short)f2bf(o[i]);
    *(bf16x8*)(out + (size_t)node * 256 + 8 * cl) = ov;
  }

  // fused layer-2 scores (both halves hold the full row after combine; each
  // 32-lane half reduces independently; lane 0 writes).
  float s2[4], d2[4];
#pragma unroll
  for (int hh = 0; hh < 4; ++hh) {
    float4 wA = *(const float4*)(ws2 + hh * 256 + 8 * cl);
    float4 wB = *(const float4*)(ws2 + hh * 256 + 8 * cl + 4);
    float4 dA = *(const float4*)(wd2 + hh * 256 + 8 * cl);
    float4 dB = *(const float4*)(wd2 + hh * 256 + 8 * cl + 4);
    s2[hh] = o[0]*wA.x + o[1]*wA.y + o[2]*wA.z + o[3]*wA.w +
             o[4]*wB.x + o[5]*wB.y + o[6]*wB.z + o[7]*wB.w;
    d2[hh] = o[0]*dA.x + o[1]*dA.y + o[2]*dA.z + o[3]*dA.w +
             o[4]*dB.x + o[5]*dB.y + o[6]*dB.z + o[7]*dB.w;
  }
  for (int mm = 1; mm < 32; mm <<= 1) {
#pragma unroll
    for (int hh = 0; hh < 4; ++hh) {
      s2[hh] += __shfl_xor(s2[hh], mm);
      d2[hh] += __shfl_xor(d2[hh], mm);
    }
  }
  if (lane == 0) {
#pragma unroll
    for (int hh = 0; hh < 4; ++hh) {
      es2[node * 4 + hh] = s2[hh];
      ed2[node * 4 + hh] = d2[hh];
    }
  }
}

// layer 2 aggregation in INPUT space (R20 wide-gather): two 32-lane halves,
// 2 edges per iteration, 16B loads; acc[4 heads][8 ch] in registers.
__global__ __launch_bounds__(256) void agg2in_kernel(
    const bf16_t* __restrict__ out1, const ushort* __restrict__ alpha,
    const int* __restrict__ rowptr, const int* __restrict__ col,
    bf16_t* __restrict__ z, int n0, int n1) {
  int node = n0 + ((blockIdx.x * blockDim.x + threadIdx.x) >> 6);
  if (node >= n1) return;
  int lane = threadIdx.x & 63;
  int half = lane >> 5;
  int cl   = lane & 31;          // channels [8cl, 8cl+8) of the out1 row
  int beg = rowptr[node], end = rowptr[node + 1];
  float acc[4][8] = {{0.f,0.f,0.f,0.f,0.f,0.f,0.f,0.f},
                     {0.f,0.f,0.f,0.f,0.f,0.f,0.f,0.f},
                     {0.f,0.f,0.f,0.f,0.f,0.f,0.f,0.f},
                     {0.f,0.f,0.f,0.f,0.f,0.f,0.f,0.f}};
  int j = beg;
  for (; j + 2 <= end; j += 2) {
    int e = j + half;
    int s = col[e];
    ushort4 q = *(const ushort4*)(alpha + (size_t)e * 4);
    bf16x8 r = *(const bf16x8*)(out1 + (size_t)s * 256 + 8 * cl);
    float a0 = h2f(q.x), a1 = h2f(q.y), a2 = h2f(q.z), a3 = h2f(q.w);
    float v[8];
#pragma unroll
    for (int i = 0; i < 8; ++i) v[i] = bf2f((ushort)r[i]);
#pragma unroll
    for (int i = 0; i < 8; ++i) {
      acc[0][i] += a0 * v[i];
      acc[1][i] += a1 * v[i];
      acc[2][i] += a2 * v[i];
      acc[3][i] += a3 * v[i];
    }
  }
  if (j < end && half == 0) {
    int s = col[j];
    ushort4 q = *(const ushort4*)(alpha + (size_t)j * 4);
    bf16x8 r = *(const bf16x8*)(out1 + (size_t)s * 256 + 8 * cl);
    float a0 = h2f(q.x), a1 = h2f(q.y), a2 = h2f(q.z), a3 = h2f(q.w);
    float v[8];
#pragma unroll
    for (int i = 0; i < 8; ++i) v[i] = bf2f((ushort)r[i]);
#pragma unroll
    for (int i = 0; i < 8; ++i) {
      acc[0][i] += a0 * v[i];
      acc[1][i] += a1 * v[i];
      acc[2][i] += a2 * v[i];
      acc[3][i] += a3 * v[i];
    }
  }
#pragma unroll
  for (int hh = 0; hh < 4; ++hh)
#pragma unroll
    for (int i = 0; i < 8; ++i) acc[hh][i] += __shfl_xor(acc[hh][i], 32);

  if (half == 0) {
    bf16_t* zr = z + (size_t)(node - n0) * 1024 + 8 * cl;
#pragma unroll
    for (int hh = 0; hh < 4; ++hh) {
      bf16x8 ov;
#pragma unroll
      for (int i = 0; i < 8; ++i) ov[i] = (short)f2bf(acc[hh][i]);
      *(bf16x8*)(zr + hh * 256) = ov;
    }
  }
}

// GEMM [M,1024] @ Wt2s[128][1024] -> out[M,128] with +b2 and fused LayerNorm.
__global__ __launch_bounds__(256) void gemm2ln_kernel(
    const bf16_t* __restrict__ Z, const bf16_t* __restrict__ Wt2s,
    const float* __restrict__ b2, const float* __restrict__ gamma,
    const float* __restrict__ beta, float* __restrict__ out, int n0, int M) {
  __shared__ __align__(16) ushort As[64 * 40];
  __shared__ __align__(16) ushort Bs[128 * 40];
  const int t    = threadIdx.x;
  const int wv   = t >> 6;
  const int lane = t & 63;
  const int m    = lane & 15;
  const int quad = lane >> 4;
  const int bm   = blockIdx.x * 64;

  f32x4 c0 = {0.f,0.f,0.f,0.f}, c1 = c0, c2 = c0, c3 = c0;
  f32x4 c4 = c0, c5 = c0, c6 = c0, c7 = c0;

  const int arow = t & 63, ak8 = t >> 6;
  for (int k0 = 0; k0 < 1024; k0 += 32) {
    int ga = clampi(bm + arow, 0, M - 1);
    *(float4*)(&As[arow * 40 + ak8 * 8]) =
        *(const float4*)(Z + (size_t)ga * 1024 + k0 + ak8 * 8);
    {
      int q = t;          // chunk: row = q>>2 (0..127), k8 = q&3
      *(float4*)(&Bs[(q >> 2) * 40 + (q & 3) * 8]) =
          *(const float4*)(Wt2s + (size_t)(q >> 2) * 1024 + k0 + (q & 3) * 8);
      q = t + 256;
      *(float4*)(&Bs[(q >> 2) * 40 + (q & 3) * 8]) =
          *(const float4*)(Wt2s + (size_t)(q >> 2) * 1024 + k0 + (q & 3) * 8);
    }
    __syncthreads();

    bf16x8 af = *(const bf16x8*)(&As[(wv * 16 + m) * 40 + quad * 8]);
    bf16x8 b0 = *(const bf16x8*)(&Bs[(0 * 16 + m) * 40 + quad * 8]);
    bf16x8 b1 = *(const bf16x8*)(&Bs[(1 * 16 + m) * 40 + quad * 8]);
    bf16x8 b2f = *(const bf16x8*)(&Bs[(2 * 16 + m) * 40 + quad * 8]);
    bf16x8 b3 = *(const bf16x8*)(&Bs[(3 * 16 + m) * 40 + quad * 8]);
    bf16x8 b4 = *(const bf16x8*)(&Bs[(4 * 16 + m) * 40 + quad * 8]);
    bf16x8 b5 = *(const bf16x8*)(&Bs[(5 * 16 + m) * 40 + quad * 8]);
    bf16x8 b6 = *(const bf16x8*)(&Bs[(6 * 16 + m) * 40 + quad * 8]);
    bf16x8 b7 = *(const bf16x8*)(&Bs[(7 * 16 + m) * 40 + quad * 8]);
    c0 = __builtin_amdgcn_mfma_f32_16x16x32_bf16(af, b0, c0, 0, 0, 0);
    c1 = __builtin_amdgcn_mfma_f32_16x16x32_bf16(af, b1, c1, 0, 0, 0);
    c2 = __builtin_amdgcn_mfma_f32_16x16x32_bf16(af, b2f, c2, 0, 0, 0);
    c3 = __builtin_amdgcn_mfma_f32_16x16x32_bf16(af, b3, c3, 0, 0, 0);
    c4 = __builtin_amdgcn_mfma_f32_16x16x32_bf16(af, b4, c4, 0, 0, 0);
    c5 = __builtin_amdgcn_mfma_f32_16x16x32_bf16(af, b5, c5, 0, 0, 0);
    c6 = __builtin_amdgcn_mfma_f32_16x16x32_bf16(af, b6, c6, 0, 0, 0);
    c7 = __builtin_amdgcn_mfma_f32_16x16x32_bf16(af, b7, c7, 0, 0, 0);
    __syncthreads();
  }

  // ----- fused +b2 and LayerNorm over the 128-wide row -----
  float b2v[8], gv[8], btv[8];
#pragma unroll
  for (int n = 0; n < 8; ++n) {
    int c = n * 16 + m;
    b2v[n] = b2[c]; gv[n] = gamma[c]; btv[n] = beta[c];
  }
#pragma unroll
  for (int r = 0; r < 4; ++r) {
    float v0 = c0[r] + b2v[0], v1 = c1[r] + b2v[1];
    float v2 = c2[r] + b2v[2], v3 = c3[r] + b2v[3];
    float v4 = c4[r] + b2v[4], v5 = c5[r] + b2v[5];
    float v6 = c6[r] + b2v[6], v7 = c7[r] + b2v[7];
    float tsum = v0 + v1 + v2 + v3 + v4 + v5 + v6 + v7;
    tsum += __shfl_xor(tsum, 1); tsum += __shfl_xor(tsum, 2);
    tsum += __shfl_xor(tsum, 4); tsum += __shfl_xor(tsum, 8);
    float mu = tsum * (1.f / 128.f);
    float d0 = v0 - mu, d1 = v1 - mu, d2 = v2 - mu, d3 = v3 - mu;
    float d4 = v4 - mu, d5 = v5 - mu, d6 = v6 - mu, d7 = v7 - mu;
    float vq = d0*d0 + d1*d1 + d2*d2 + d3*d3 + d4*d4 + d5*d5 + d6*d6 + d7*d7;
    vq += __shfl_xor(vq, 1); vq += __shfl_xor(vq, 2);
    vq += __shfl_xor(vq, 4); vq += __shfl_xor(vq, 8);
    float rinv = rsqrtf(vq * (1.f / 128.f) + 1e-5f);
    int row = bm + wv * 16 + quad * 4 + r;
    if (row < M) {
      float* orow = out + (size_t)(n0 + row) * 128;
      orow[0 * 16 + m] = d0 * rinv * gv[0] + btv[0];
      orow[1 * 16 + m] = d1 * rinv * gv[1] + btv[1];
      orow[2 * 16 + m] = d2 * rinv * gv[2] + btv[2];
      orow[3 * 16 + m] = d3 * rinv * gv[3] + btv[3];
      orow[4 * 16 + m] = d4 * rinv * gv[4] + btv[4];
      orow[5 * 16 + m] = d5 * rinv * gv[5] + btv[5];
      orow[6 * 16 + m] = d6 * rinv * gv[6] + btv[6];
      orow[7 * 16 + m] = d7 * rinv * gv[7] + btv[7];
    }
  }
}

// ------------------------------- launcher ----------------------------------

extern "C" void kernel_launch(void* const* d_in, const int* in_sizes, int n_in,
                              void* d_out, int out_size, void* d_ws, size_t ws_size,
                              hipStream_t stream) {
  const float* x     = (const float*)d_in[0];
  const void*  ei    = d_in[1];
  const float* W1    = (const float*)d_in[2];
  const float* asrc1 = (const float*)d_in[3];
  const float* adst1 = (const float*)d_in[4];
  const float* b1    = (const float*)d_in[5];
  const float* W2    = (const float*)d_in[6];
  const float* asrc2 = (const float*)d_in[7];
  const float* adst2 = (const float*)d_in[8];
  const float* b2    = (const float*)d_in[9];
  const float* gamma = (const float*)d_in[10];
  const float* beta  = (const float*)d_in[11];
  float* out = (float*)d_out;

  const int E0 = in_sizes[1] / 2;       // 800000 raw edges
  const int ET = E0 + NNODES;           // + self loops

  // ws layout (< 89.7 MB). Overlays (R16-verified):
  //   z      [0,51.2M)      agg2in..gemm2ln (25K x 1024 bf16, 2 passes)
  //   pairs  [25.6M,32.4M)  binscatter..csrbin (inside h1 region, dead then)
  //   h1     [25.6M,51.2M)  gemm1..agg1
  //   xb     [51.2M,64M)    conv..gemm1
  //   out1   [51.2M,76.8M)  agg1..agg2in
  //   alpha  [76.8M,83.6M)  per-layer reuse (fp16 half4) — NO pairs overlay
  char* w = (char*)d_ws;
  bf16_t* z      = (bf16_t*)(w + 0);          // 25000*1024*2 = 51.2 MB
  int2*   pairs  = (int2*)(w + 25600000);     // 850000*8 = 6.8 MB (pre-gemm1)
  bf16_t* h1     = (bf16_t*)(w + 25600000);
  bf16_t* xb     = (bf16_t*)(w + 51200000);
  bf16_t* out1   = (bf16_t*)(w + 51200000);
  ushort* alpha  = (ushort*)(w + 76800000);   // 850000*8 = 6.8 MB
  float* es    = (float*)(w + 83600000);      // 800 KB
  float* ed    = (float*)(w + 84400000);      // 800 KB
  bf16_t* Wt1    = (bf16_t*)(w + 85200000);   // 64 KB
  bf16_t* Wt2s   = (bf16_t*)(w + 85300000);   // 128*1024*2 = 256 KB
  float* ws2   = (float*)(w + 85564000);      // 4 KB
  float* wd2   = (float*)(w + 85570000);      // 4 KB
  int* rowptr   = (int*)(w + 85600000);       // 50001 ints
  int* binStart = (int*)(w + 85800064);       // 197 ints
  int* binTotal = (int*)(w + 85801000);       // 196 ints
  int* blockBin = (int*)(w + 85802000);       // 196*256 ints = 200.7 KB
  int* col      = (int*)(w + 86200192);       // 3.4 MB
  int* mode     = (int*)(w + 89600704);

  // ---- prep: bf16 conversions + layer-2 weight prep ----
  convert_x_kernel<<<(NNODES * 128 / 4 + 255) / 256, 256, 0, stream>>>(x, xb,
                                                                       NNODES * 128 / 4);
  transpose_w_kernel<128, 256><<<256, 128, 0, stream>>>(W1, Wt1);
  proj2_kernel<<<4, 256, 0, stream>>>(W2, asrc2, adst2, ws2, wd2);
  wstack_kernel<<<128, 1024, 0, stream>>>(W2, Wt2s);

  // ---- edge dtype detect + CSR build (two-level counting sort) ----
  const int CHUNK = (ET + ABLOCKS - 1) / ABLOCKS;
  detect_kernel<<<1, 256, 0, stream>>>((const int*)ei, mode);
  binhist_kernel<<<ABLOCKS, 256, 0, stream>>>(ei, mode, blockBin, E0, ET, CHUNK);
  binscanA_kernel<<<NBINS, ABLOCKS, 0, stream>>>(blockBin, binTotal);
  binscanB_kernel<<<1, 256, 0, stream>>>(binTotal, binStart);
  binscatter_kernel<<<ABLOCKS, 256, 0, stream>>>(ei, mode, blockBin, binStart, pairs,
                                                 E0, ET, CHUNK);
  csrbin_kernel<<<NBINS, 256, 0, stream>>>(pairs, binStart, rowptr, col);

  const int MB = (NNODES + 63) / 64;       // 782
  const int NODE_BLOCKS = (NNODES + 3) / 4;       // 64-lane-per-node kernels
  const int NODE_BLOCKS16 = (NNODES * 16 + 255) / 256;  // 16-lane-per-node

  // ---- layer 1 (scores fused into gemm1 epilogue) ----
  gemm1s_kernel<<<dim3(MB, 4), 256, 0, stream>>>(xb, Wt1, h1, asrc1, adst1,
                                                 es, ed, NNODES);
  alpha_kernel<<<NODE_BLOCKS16, 256, 0, stream>>>(es, ed, rowptr, col, alpha);
  aggregate1_kernel<<<NODE_BLOCKS, 256, 0, stream>>>(h1, alpha, rowptr, col, b1,
                                                     out1, ws2, wd2, es, ed);

  // ---- layer 2 (scores fused into aggregate1 epilogue) ----
  alpha_kernel<<<NODE_BLOCKS16, 256, 0, stream>>>(es, ed, rowptr, col, alpha);

  const int HALF = NNODES / 2;                       // 25000
  const int AB = (HALF * 64 + 255) / 256;            // 6250 blocks (4 nodes each)
  const int GB = (HALF + 63) / 64;                   // 391 blocks
  agg2in_kernel<<<AB, 256, 0, stream>>>(out1, alpha, rowptr, col, z, 0, HALF);
  gemm2ln_kernel<<<GB, 256, 0, stream>>>(z, Wt2s, b2, gamma, beta, out, 0, HALF);
  agg2in_kernel<<<AB, 256, 0, stream>>>(out1, alpha, rowptr, col, z, HALF, NNODES);
  gemm2ln_kernel<<<GB, 256, 0, stream>>>(z, Wt2s, b2, gamma, beta, out, HALF, HALF);
}

// Round 10
// 390.100 us; speedup vs baseline: 1.1155x; 1.1155x over previous
//
#include <hip/hip_runtime.h>
#include <hip/hip_fp16.h>
#include <cstdint>
#include <cstddef>

// ---------------------------------------------------------------------------
// GAT x2 + LayerNorm on MI355X.
// R16: counting-sort CSR + overlay fix (verified 434us).
// R19: scores fused into gemm1 epilogue + aggregate1 epilogue (verified 408us).
// R20: wide-gather (16B/lane, 2 edges/instr) — REGRESSED 435us: MLP dropped
//   4->1 loads in flight, occupancy 67->45. Lesson: keep >=4 independent
//   gathers per wave iteration.
// R21 (this round): revert aggregates to R19 form; keep 16-lane alpha
//   (safe R20 piece); fold edge-dtype detection into binhist/binscatter
//   (one fewer dispatch, no mode round-trip).
// ---------------------------------------------------------------------------

constexpr int NNODES = 50000;
constexpr int NBINS = (NNODES + 255) >> 8;   // 196 coarse bins (256 nodes each)
constexpr int ABLOCKS = 256;                 // binning grid

typedef unsigned short bf16_t;
typedef __attribute__((ext_vector_type(8))) short bf16x8;
typedef __attribute__((ext_vector_type(4))) float f32x4;

__device__ __forceinline__ float bf2f(bf16_t b) {
  return __uint_as_float(((unsigned int)b) << 16);
}
__device__ __forceinline__ bf16_t f2bf(float f) {
  unsigned int u = __float_as_uint(f);
  u += 0x7fffu + ((u >> 16) & 1u);   // round to nearest even
  return (bf16_t)(u >> 16);
}
__device__ __forceinline__ float4 bf4_to_f4(ushort4 v) {
  return make_float4(bf2f(v.x), bf2f(v.y), bf2f(v.z), bf2f(v.w));
}
__device__ __forceinline__ ushort4 f4_to_bf4(float4 v) {
  return make_ushort4(f2bf(v.x), f2bf(v.y), f2bf(v.z), f2bf(v.w));
}
__device__ __forceinline__ ushort f2h(float f) {
  __half h = __float2half_rn(f);
  return *(ushort*)&h;
}
__device__ __forceinline__ float h2f(ushort u) {
  __half h; *(ushort*)&h = u;
  return __half2float(h);
}
__device__ __forceinline__ float lrelu(float x) { return x > 0.f ? x : 0.2f * x; }
__device__ __forceinline__ int clampi(int v, int lo, int hi) {
  return v < lo ? lo : (v > hi ? hi : v);
}
__device__ __forceinline__ int load_edge(const void* ei, int mode, int idx) {
  if (mode) return (int)((const long long*)ei)[idx];
  return ((const int*)ei)[idx];
}

// Per-block edge-dtype detection (same 256 samples as the old detect_kernel,
// deterministic): int64 edge data has zero high-words at odd int32 positions.
__device__ __forceinline__ int block_detect_mode(const int* ei32, int* nz_sm) {
  if (threadIdx.x == 0) *nz_sm = 0;
  __syncthreads();
  if (threadIdx.x < 256 && ei32[2 * threadIdx.x + 1] != 0) atomicAdd(nz_sm, 1);
  __syncthreads();
  return (*nz_sm == 0) ? 1 : 0;
}

// ------------------------------ prep kernels -------------------------------

__global__ void convert_x_kernel(const float* __restrict__ x, bf16_t* __restrict__ xb,
                                 int n4) {
  int i = blockIdx.x * blockDim.x + threadIdx.x;
  if (i >= n4) return;
  float4 v = *(const float4*)(x + 4 * (size_t)i);
  *(ushort4*)(xb + 4 * (size_t)i) = f4_to_bf4(v);
}

template <int K, int NC>
__global__ void transpose_w_kernel(const float* __restrict__ W, bf16_t* __restrict__ Wt) {
  int n = blockIdx.x;
  int k = threadIdx.x;
  Wt[(size_t)n * K + k] = f2bf(W[(size_t)k * NC + n]);
}

// ws2[h,k] = sum_c W2[k, h*128+c] * a_src2[h,c]   (and wd2 with a_dst2)
__global__ void proj2_kernel(const float* __restrict__ W2,
                             const float* __restrict__ asrc2,
                             const float* __restrict__ adst2,
                             float* __restrict__ ws2, float* __restrict__ wd2) {
  int h = blockIdx.x;      // 0..3
  int k = threadIdx.x;     // 0..255
  const float* wrow = W2 + (size_t)k * 512 + h * 128;
  const float* as = asrc2 + h * 128;
  const float* ad = adst2 + h * 128;
  float s = 0.f, d = 0.f;
  for (int c = 0; c < 128; ++c) { s += wrow[c] * as[c]; d += wrow[c] * ad[c]; }
  ws2[h * 256 + k] = s;
  wd2[h * 256 + k] = d;
}

// Wt2s[c][h*256+k] = W2[k, h*128+c] * 0.25  (stacked weight, transposed, bf16)
__global__ __launch_bounds__(1024) void wstack_kernel(const float* __restrict__ W2,
                                                      bf16_t* __restrict__ Wt2s) {
  int c = blockIdx.x;      // 0..127
  int t = threadIdx.x;     // 0..1023 : h = t>>8, k = t&255
  int h = t >> 8, k = t & 255;
  Wt2s[(size_t)c * 1024 + t] = f2bf(W2[(size_t)k * 512 + h * 128 + c] * 0.25f);
}

// --------------------- CSR build: two-level counting sort ------------------
__global__ __launch_bounds__(256) void binhist_kernel(
    const void* __restrict__ ei, int* __restrict__ blockBin,
    int e0, int et, int chunk) {
  __shared__ int h[NBINS];
  __shared__ int nzsm;
  int mode = block_detect_mode((const int*)ei, &nzsm);
  int t = threadIdx.x, blk = blockIdx.x;
  for (int i = t; i < NBINS; i += 256) h[i] = 0;
  __syncthreads();
  int lo = blk * chunk, hi = min(et, lo + chunk);
  for (int e = lo + t; e < hi; e += 256) {
    int dst = (e < e0) ? load_edge(ei, mode, e0 + e) : (e - e0);
    dst = clampi(dst, 0, NNODES - 1);
    atomicAdd(&h[dst >> 8], 1);
  }
  __syncthreads();
  for (int i = t; i < NBINS; i += 256) blockBin[i * ABLOCKS + blk] = h[i];
}

__global__ __launch_bounds__(ABLOCKS) void binscanA_kernel(int* __restrict__ blockBin,
                                                           int* __restrict__ binTotal) {
  __shared__ int sm[ABLOCKS];
  int b = blockIdx.x, t = threadIdx.x;
  int orig = blockBin[b * ABLOCKS + t];
  sm[t] = orig;
  __syncthreads();
  for (int off = 1; off < ABLOCKS; off <<= 1) {
    int u = (t >= off) ? sm[t - off] : 0;
    __syncthreads();
    sm[t] += u;
    __syncthreads();
  }
  blockBin[b * ABLOCKS + t] = sm[t] - orig;
  if (t == ABLOCKS - 1) binTotal[b] = sm[ABLOCKS - 1];
}

__global__ __launch_bounds__(256) void binscanB_kernel(const int* __restrict__ binTotal,
                                                       int* __restrict__ binStart) {
  __shared__ int sm[256];
  int t = threadIdx.x;
  int orig = (t < NBINS) ? binTotal[t] : 0;
  sm[t] = orig;
  __syncthreads();
  for (int off = 1; off < 256; off <<= 1) {
    int u = (t >= off) ? sm[t - off] : 0;
    __syncthreads();
    sm[t] += u;
    __syncthreads();
  }
  if (t < NBINS) binStart[t] = sm[t] - orig;
  if (t == 255) binStart[NBINS] = sm[255];
}

__global__ __launch_bounds__(256) void binscatter_kernel(
    const void* __restrict__ ei, const int* __restrict__ blockBin,
    const int* __restrict__ binStart, int2* __restrict__ pairs,
    int e0, int et, int chunk) {
  __shared__ int cur[NBINS];
  __shared__ int nzsm;
  int mode = block_detect_mode((const int*)ei, &nzsm);
  int t = threadIdx.x, blk = blockIdx.x;
  for (int i = t; i < NBINS; i += 256)
    cur[i] = binStart[i] + blockBin[i * ABLOCKS + blk];
  __syncthreads();
  int lo = blk * chunk, hi = min(et, lo + chunk);
  for (int e = lo + t; e < hi; e += 256) {
    int src, dst;
    if (e < e0) { src = load_edge(ei, mode, e); dst = load_edge(ei, mode, e0 + e); }
    else        { src = dst = e - e0; }
    src = clampi(src, 0, NNODES - 1);
    dst = clampi(dst, 0, NNODES - 1);
    int p = atomicAdd(&cur[dst >> 8], 1);
    pairs[p] = make_int2(src, dst);
  }
}

// B: per-bin CSR finalize — defensive clamp keeps LDS safe.
__global__ __launch_bounds__(256) void csrbin_kernel(const int2* __restrict__ pairs,
                                                     const int* __restrict__ binStart,
                                                     int* __restrict__ rowptr,
                                                     int* __restrict__ col) {
  __shared__ int cnt[256];
  __shared__ int sc[256];
  int b = blockIdx.x, t = threadIdx.x;
  int node0 = b << 8;
  int es = binStart[b], ee = binStart[b + 1];
  cnt[t] = 0;
  __syncthreads();
  for (int p = es + t; p < ee; p += 256) {
    int2 pr = pairs[p];
    int d = clampi(pr.y - node0, 0, 255);
    atomicAdd(&cnt[d], 1);
  }
  __syncthreads();
  int orig = cnt[t];
  sc[t] = orig;
  __syncthreads();
  for (int off = 1; off < 256; off <<= 1) {
    int u = (t >= off) ? sc[t - off] : 0;
    __syncthreads();
    sc[t] += u;
    __syncthreads();
  }
  int excl = sc[t] - orig;
  if (node0 + t < NNODES) rowptr[node0 + t] = es + excl;
  if (b == NBINS - 1 && t == 0) rowptr[NNODES] = ee;
  cnt[t] = excl;
  __syncthreads();
  for (int p = es + t; p < ee; p += 256) {
    int2 pr = pairs[p];
    int d = clampi(pr.y - node0, 0, 255);
    int pos = atomicAdd(&cnt[d], 1);
    col[es + pos] = pr.x;
  }
}

// --------------- MFMA GEMM (layer 1) with fused layer-1 scores -------------
__global__ __launch_bounds__(256) void gemm1s_kernel(
    const bf16_t* __restrict__ A, const bf16_t* __restrict__ Wt,
    bf16_t* __restrict__ C, const float* __restrict__ asrc,
    const float* __restrict__ adst, float* __restrict__ es,
    float* __restrict__ ed, int M) {
  __shared__ __align__(16) ushort As[64 * 40];
  __shared__ __align__(16) ushort Bs[64 * 40];
  const int t    = threadIdx.x;
  const int wv   = t >> 6;
  const int lane = t & 63;
  const int m    = lane & 15;
  const int quad = lane >> 4;
  const int bm = blockIdx.x * 64, bn = blockIdx.y * 64;
  const int srow = t & 63;
  const int sk8  = t >> 6;

  f32x4 acc0 = {0.f, 0.f, 0.f, 0.f};
  f32x4 acc1 = {0.f, 0.f, 0.f, 0.f};
  f32x4 acc2 = {0.f, 0.f, 0.f, 0.f};
  f32x4 acc3 = {0.f, 0.f, 0.f, 0.f};

  for (int k0 = 0; k0 < 128; k0 += 32) {
    int ga = clampi(bm + srow, 0, M - 1);
    float4 av = *(const float4*)(A + (size_t)ga * 128 + k0 + sk8 * 8);
    *(float4*)(&As[srow * 40 + sk8 * 8]) = av;
    float4 bv = *(const float4*)(Wt + (size_t)(bn + srow) * 128 + k0 + sk8 * 8);
    *(float4*)(&Bs[srow * 40 + sk8 * 8]) = bv;
    __syncthreads();

    bf16x8 af = *(const bf16x8*)(&As[(wv * 16 + m) * 40 + quad * 8]);
    bf16x8 b0 = *(const bf16x8*)(&Bs[(0 * 16 + m) * 40 + quad * 8]);
    bf16x8 b1 = *(const bf16x8*)(&Bs[(1 * 16 + m) * 40 + quad * 8]);
    bf16x8 b2 = *(const bf16x8*)(&Bs[(2 * 16 + m) * 40 + quad * 8]);
    bf16x8 b3 = *(const bf16x8*)(&Bs[(3 * 16 + m) * 40 + quad * 8]);
    acc0 = __builtin_amdgcn_mfma_f32_16x16x32_bf16(af, b0, acc0, 0, 0, 0);
    acc1 = __builtin_amdgcn_mfma_f32_16x16x32_bf16(af, b1, acc1, 0, 0, 0);
    acc2 = __builtin_amdgcn_mfma_f32_16x16x32_bf16(af, b2, acc2, 0, 0, 0);
    acc3 = __builtin_amdgcn_mfma_f32_16x16x32_bf16(af, b3, acc3, 0, 0, 0);
    __syncthreads();
  }

  float as0 = asrc[bn +  0 + m], as1 = asrc[bn + 16 + m];
  float as2 = asrc[bn + 32 + m], as3 = asrc[bn + 48 + m];
  float ad0 = adst[bn +  0 + m], ad1 = adst[bn + 16 + m];
  float ad2 = adst[bn + 32 + m], ad3 = adst[bn + 48 + m];
  const int hd = bn >> 6;

#pragma unroll
  for (int r = 0; r < 4; ++r) {
    int row = bm + wv * 16 + quad * 4 + r;
    float ps = acc0[r] * as0 + acc1[r] * as1 + acc2[r] * as2 + acc3[r] * as3;
    float pd = acc0[r] * ad0 + acc1[r] * ad1 + acc2[r] * ad2 + acc3[r] * ad3;
    for (int mm = 1; mm < 16; mm <<= 1) {
      ps += __shfl_xor(ps, mm);
      pd += __shfl_xor(pd, mm);
    }
    if (row < M) {
      size_t base = (size_t)row * 256 + bn;
      C[base +  0 + m] = f2bf(acc0[r]);
      C[base + 16 + m] = f2bf(acc1[r]);
      C[base + 32 + m] = f2bf(acc2[r]);
      C[base + 48 + m] = f2bf(acc3[r]);
      if (m == 0) {
        es[row * 4 + hd] = ps;
        ed[row * 4 + hd] = pd;
      }
    }
  }
}

// --------------------------- alpha precompute (fp16) -----------------------
// 16 lanes per node (4 nodes/wave) — avg degree ~17.
__global__ __launch_bounds__(256) void alpha_kernel(
    const float* __restrict__ es, const float* __restrict__ ed,
    const int* __restrict__ rowptr, const int* __restrict__ col,
    ushort* __restrict__ alpha) {
  int node = (blockIdx.x * blockDim.x + threadIdx.x) >> 4;
  if (node >= NNODES) return;
  int l16 = threadIdx.x & 15;
  int beg = rowptr[node], end = rowptr[node + 1];
  float4 edv = *(const float4*)(ed + node * 4);
  float4 l = make_float4(0.f, 0.f, 0.f, 0.f);
  for (int p = beg + l16; p < end; p += 16) {
    int s = col[p];
    float4 e = *(const float4*)(es + s * 4);
    l.x += __expf(lrelu(e.x + edv.x));
    l.y += __expf(lrelu(e.y + edv.y));
    l.z += __expf(lrelu(e.z + edv.z));
    l.w += __expf(lrelu(e.w + edv.w));
  }
  for (int off = 1; off < 16; off <<= 1) {
    l.x += __shfl_xor(l.x, off);
    l.y += __shfl_xor(l.y, off);
    l.z += __shfl_xor(l.z, off);
    l.w += __shfl_xor(l.w, off);
  }
  float4 il = make_float4(1.f / (l.x + 1e-16f), 1.f / (l.y + 1e-16f),
                          1.f / (l.z + 1e-16f), 1.f / (l.w + 1e-16f));
  for (int p = beg + l16; p < end; p += 16) {
    int s = col[p];
    float4 e = *(const float4*)(es + s * 4);
    ushort4 a;
    a.x = f2h(__expf(lrelu(e.x + edv.x)) * il.x);
    a.y = f2h(__expf(lrelu(e.y + edv.y)) * il.y);
    a.z = f2h(__expf(lrelu(e.z + edv.z)) * il.z);
    a.w = f2h(__expf(lrelu(e.w + edv.w)) * il.w);
    *(ushort4*)(alpha + (size_t)p * 4) = a;
  }
}

// ------------------------------- aggregation -------------------------------
// layer 1 (R19-proven): wave per node; lane holds 4 channels at 4*lane
// (head = lane>>4); unroll x4 (4 independent gathers in flight).
// Epilogue: fused layer-2 scores from the out1 row.
__global__ __launch_bounds__(256) void aggregate1_kernel(
    const bf16_t* __restrict__ h, const ushort* __restrict__ alpha,
    const int* __restrict__ rowptr, const int* __restrict__ col,
    const float* __restrict__ b1, bf16_t* __restrict__ out,
    const float* __restrict__ ws2, const float* __restrict__ wd2,
    float* __restrict__ es2, float* __restrict__ ed2) {
  int node = (blockIdx.x * blockDim.x + threadIdx.x) >> 6;
  if (node >= NNODES) return;
  int lane = threadIdx.x & 63;
  int head = lane >> 4;
  int beg = rowptr[node], end = rowptr[node + 1];
  const ushort4* hb = (const ushort4*)h;   // row = 64 ushort4
  float4 acc = make_float4(0.f, 0.f, 0.f, 0.f);
  int j = beg;
  for (; j + 4 <= end; j += 4) {
    int s0 = col[j], s1 = col[j + 1], s2 = col[j + 2], s3 = col[j + 3];
    ushort u0 = alpha[(size_t)(j + 0) * 4 + head];
    ushort u1 = alpha[(size_t)(j + 1) * 4 + head];
    ushort u2 = alpha[(size_t)(j + 2) * 4 + head];
    ushort u3 = alpha[(size_t)(j + 3) * 4 + head];
    ushort4 r0 = hb[(size_t)s0 * 64 + lane];
    ushort4 r1 = hb[(size_t)s1 * 64 + lane];
    ushort4 r2 = hb[(size_t)s2 * 64 + lane];
    ushort4 r3 = hb[(size_t)s3 * 64 + lane];
    float a0 = h2f(u0), a1 = h2f(u1), a2 = h2f(u2), a3 = h2f(u3);
    float4 v0 = bf4_to_f4(r0), v1 = bf4_to_f4(r1);
    float4 v2 = bf4_to_f4(r2), v3 = bf4_to_f4(r3);
    acc.x += a0 * v0.x + a1 * v1.x + a2 * v2.x + a3 * v3.x;
    acc.y += a0 * v0.y + a1 * v1.y + a2 * v2.y + a3 * v3.y;
    acc.z += a0 * v0.z + a1 * v1.z + a2 * v2.z + a3 * v3.z;
    acc.w += a0 * v0.w + a1 * v1.w + a2 * v2.w + a3 * v3.w;
  }
  for (; j < end; ++j) {
    int s0 = col[j];
    float a0 = h2f(alpha[(size_t)j * 4 + head]);
    float4 v0 = bf4_to_f4(hb[(size_t)s0 * 64 + lane]);
    acc.x += a0 * v0.x;
    acc.y += a0 * v0.y;
    acc.z += a0 * v0.z;
    acc.w += a0 * v0.w;
  }
  float4 bb = *(const float4*)(b1 + 4 * lane);
  float4 o;
  o.x = fmaxf(acc.x + bb.x, 0.f);
  o.y = fmaxf(acc.y + bb.y, 0.f);
  o.z = fmaxf(acc.z + bb.z, 0.f);
  o.w = fmaxf(acc.w + bb.w, 0.f);
  *(ushort4*)(out + (size_t)node * 256 + 4 * lane) = f4_to_bf4(o);

  // fused layer-2 scores: es2/ed2[node][h] = out1row . ws2/wd2[h]
  float s2[4], d2[4];
#pragma unroll
  for (int hh = 0; hh < 4; ++hh) {
    float4 wv = *(const float4*)(ws2 + hh * 256 + 4 * lane);
    float4 dv = *(const float4*)(wd2 + hh * 256 + 4 * lane);
    s2[hh] = o.x * wv.x + o.y * wv.y + o.z * wv.z + o.w * wv.w;
    d2[hh] = o.x * dv.x + o.y * dv.y + o.z * dv.z + o.w * dv.w;
  }
  for (int mm = 1; mm < 64; mm <<= 1) {
#pragma unroll
    for (int hh = 0; hh < 4; ++hh) {
      s2[hh] += __shfl_xor(s2[hh], mm);
      d2[hh] += __shfl_xor(d2[hh], mm);
    }
  }
  if (lane == 0) {
#pragma unroll
    for (int hh = 0; hh < 4; ++hh) {
      es2[node * 4 + hh] = s2[hh];
      ed2[node * 4 + hh] = d2[hh];
    }
  }
}

// layer 2 aggregation in INPUT space (R19-proven): wave per node; lane covers
// 4 channels at 4*lane; unroll x4; acc[4 heads][4 ch].
__device__ __forceinline__ void fma4h(float (&acc)[4][4], ushort4 q, float4 v) {
  float f0 = h2f(q.x), f1 = h2f(q.y), f2 = h2f(q.z), f3 = h2f(q.w);
  acc[0][0] += f0 * v.x; acc[0][1] += f0 * v.y; acc[0][2] += f0 * v.z; acc[0][3] += f0 * v.w;
  acc[1][0] += f1 * v.x; acc[1][1] += f1 * v.y; acc[1][2] += f1 * v.z; acc[1][3] += f1 * v.w;
  acc[2][0] += f2 * v.x; acc[2][1] += f2 * v.y; acc[2][2] += f2 * v.z; acc[2][3] += f2 * v.w;
  acc[3][0] += f3 * v.x; acc[3][1] += f3 * v.y; acc[3][2] += f3 * v.z; acc[3][3] += f3 * v.w;
}

__global__ __launch_bounds__(256) void agg2in_kernel(
    const bf16_t* __restrict__ out1, const ushort* __restrict__ alpha,
    const int* __restrict__ rowptr, const int* __restrict__ col,
    bf16_t* __restrict__ z, int n0, int n1) {
  int node = n0 + ((blockIdx.x * blockDim.x + threadIdx.x) >> 6);
  if (node >= n1) return;
  int lane = threadIdx.x & 63;
  int beg = rowptr[node], end = rowptr[node + 1];
  const ushort4* hb = (const ushort4*)out1;   // row = 64 ushort4
  float acc[4][4] = {{0.f,0.f,0.f,0.f},{0.f,0.f,0.f,0.f},
                     {0.f,0.f,0.f,0.f},{0.f,0.f,0.f,0.f}};
  int j = beg;
  for (; j + 4 <= end; j += 4) {
    int s0 = col[j], s1 = col[j + 1], s2 = col[j + 2], s3 = col[j + 3];
    ushort4 q0 = *(const ushort4*)(alpha + (size_t)(j + 0) * 4);
    ushort4 q1 = *(const ushort4*)(alpha + (size_t)(j + 1) * 4);
    ushort4 q2 = *(const ushort4*)(alpha + (size_t)(j + 2) * 4);
    ushort4 q3 = *(const ushort4*)(alpha + (size_t)(j + 3) * 4);
    ushort4 r0 = hb[(size_t)s0 * 64 + lane];
    ushort4 r1 = hb[(size_t)s1 * 64 + lane];
    ushort4 r2 = hb[(size_t)s2 * 64 + lane];
    ushort4 r3 = hb[(size_t)s3 * 64 + lane];
    fma4h(acc, q0, bf4_to_f4(r0));
    fma4h(acc, q1, bf4_to_f4(r1));
    fma4h(acc, q2, bf4_to_f4(r2));
    fma4h(acc, q3, bf4_to_f4(r3));
  }
  for (; j < end; ++j) {
    int s0 = col[j];
    ushort4 q0 = *(const ushort4*)(alpha + (size_t)j * 4);
    ushort4 r0 = hb[(size_t)s0 * 64 + lane];
    fma4h(acc, q0, bf4_to_f4(r0));
  }
  bf16_t* zr = z + (size_t)(node - n0) * 1024 + 4 * lane;
#pragma unroll
  for (int h = 0; h < 4; ++h) {
    *(ushort4*)(zr + h * 256) =
        f4_to_bf4(make_float4(acc[h][0], acc[h][1], acc[h][2], acc[h][3]));
  }
}

// GEMM [M,1024] @ Wt2s[128][1024] -> out[M,128] with +b2 and fused LayerNorm.
__global__ __launch_bounds__(256) void gemm2ln_kernel(
    const bf16_t* __restrict__ Z, const bf16_t* __restrict__ Wt2s,
    const float* __restrict__ b2, const float* __restrict__ gamma,
    const float* __restrict__ beta, float* __restrict__ out, int n0, int M) {
  __shared__ __align__(16) ushort As[64 * 40];
  __shared__ __align__(16) ushort Bs[128 * 40];
  const int t    = threadIdx.x;
  const int wv   = t >> 6;
  const int lane = t & 63;
  const int m    = lane & 15;
  const int quad = lane >> 4;
  const int bm   = blockIdx.x * 64;

  f32x4 c0 = {0.f,0.f,0.f,0.f}, c1 = c0, c2 = c0, c3 = c0;
  f32x4 c4 = c0, c5 = c0, c6 = c0, c7 = c0;

  const int arow = t & 63, ak8 = t >> 6;
  for (int k0 = 0; k0 < 1024; k0 += 32) {
    int ga = clampi(bm + arow, 0, M - 1);
    *(float4*)(&As[arow * 40 + ak8 * 8]) =
        *(const float4*)(Z + (size_t)ga * 1024 + k0 + ak8 * 8);
    {
      int q = t;          // chunk: row = q>>2 (0..127), k8 = q&3
      *(float4*)(&Bs[(q >> 2) * 40 + (q & 3) * 8]) =
          *(const float4*)(Wt2s + (size_t)(q >> 2) * 1024 + k0 + (q & 3) * 8);
      q = t + 256;
      *(float4*)(&Bs[(q >> 2) * 40 + (q & 3) * 8]) =
          *(const float4*)(Wt2s + (size_t)(q >> 2) * 1024 + k0 + (q & 3) * 8);
    }
    __syncthreads();

    bf16x8 af = *(const bf16x8*)(&As[(wv * 16 + m) * 40 + quad * 8]);
    bf16x8 b0 = *(const bf16x8*)(&Bs[(0 * 16 + m) * 40 + quad * 8]);
    bf16x8 b1 = *(const bf16x8*)(&Bs[(1 * 16 + m) * 40 + quad * 8]);
    bf16x8 b2f = *(const bf16x8*)(&Bs[(2 * 16 + m) * 40 + quad * 8]);
    bf16x8 b3 = *(const bf16x8*)(&Bs[(3 * 16 + m) * 40 + quad * 8]);
    bf16x8 b4 = *(const bf16x8*)(&Bs[(4 * 16 + m) * 40 + quad * 8]);
    bf16x8 b5 = *(const bf16x8*)(&Bs[(5 * 16 + m) * 40 + quad * 8]);
    bf16x8 b6 = *(const bf16x8*)(&Bs[(6 * 16 + m) * 40 + quad * 8]);
    bf16x8 b7 = *(const bf16x8*)(&Bs[(7 * 16 + m) * 40 + quad * 8]);
    c0 = __builtin_amdgcn_mfma_f32_16x16x32_bf16(af, b0, c0, 0, 0, 0);
    c1 = __builtin_amdgcn_mfma_f32_16x16x32_bf16(af, b1, c1, 0, 0, 0);
    c2 = __builtin_amdgcn_mfma_f32_16x16x32_bf16(af, b2f, c2, 0, 0, 0);
    c3 = __builtin_amdgcn_mfma_f32_16x16x32_bf16(af, b3, c3, 0, 0, 0);
    c4 = __builtin_amdgcn_mfma_f32_16x16x32_bf16(af, b4, c4, 0, 0, 0);
    c5 = __builtin_amdgcn_mfma_f32_16x16x32_bf16(af, b5, c5, 0, 0, 0);
    c6 = __builtin_amdgcn_mfma_f32_16x16x32_bf16(af, b6, c6, 0, 0, 0);
    c7 = __builtin_amdgcn_mfma_f32_16x16x32_bf16(af, b7, c7, 0, 0, 0);
    __syncthreads();
  }

  // ----- fused +b2 and LayerNorm over the 128-wide row -----
  float b2v[8], gv[8], btv[8];
#pragma unroll
  for (int n = 0; n < 8; ++n) {
    int c = n * 16 + m;
    b2v[n] = b2[c]; gv[n] = gamma[c]; btv[n] = beta[c];
  }
#pragma unroll
  for (int r = 0; r < 4; ++r) {
    float v0 = c0[r] + b2v[0], v1 = c1[r] + b2v[1];
    float v2 = c2[r] + b2v[2], v3 = c3[r] + b2v[3];
    float v4 = c4[r] + b2v[4], v5 = c5[r] + b2v[5];
    float v6 = c6[r] + b2v[6], v7 = c7[r] + b2v[7];
    float tsum = v0 + v1 + v2 + v3 + v4 + v5 + v6 + v7;
    tsum += __shfl_xor(tsum, 1); tsum += __shfl_xor(tsum, 2);
    tsum += __shfl_xor(tsum, 4); tsum += __shfl_xor(tsum, 8);
    float mu = tsum * (1.f / 128.f);
    float d0 = v0 - mu, d1 = v1 - mu, d2 = v2 - mu, d3 = v3 - mu;
    float d4 = v4 - mu, d5 = v5 - mu, d6 = v6 - mu, d7 = v7 - mu;
    float vq = d0*d0 + d1*d1 + d2*d2 + d3*d3 + d4*d4 + d5*d5 + d6*d6 + d7*d7;
    vq += __shfl_xor(vq, 1); vq += __shfl_xor(vq, 2);
    vq += __shfl_xor(vq, 4); vq += __shfl_xor(vq, 8);
    float rinv = rsqrtf(vq * (1.f / 128.f) + 1e-5f);
    int row = bm + wv * 16 + quad * 4 + r;
    if (row < M) {
      float* orow = out + (size_t)(n0 + row) * 128;
      orow[0 * 16 + m] = d0 * rinv * gv[0] + btv[0];
      orow[1 * 16 + m] = d1 * rinv * gv[1] + btv[1];
      orow[2 * 16 + m] = d2 * rinv * gv[2] + btv[2];
      orow[3 * 16 + m] = d3 * rinv * gv[3] + btv[3];
      orow[4 * 16 + m] = d4 * rinv * gv[4] + btv[4];
      orow[5 * 16 + m] = d5 * rinv * gv[5] + btv[5];
      orow[6 * 16 + m] = d6 * rinv * gv[6] + btv[6];
      orow[7 * 16 + m] = d7 * rinv * gv[7] + btv[7];
    }
  }
}

// ------------------------------- launcher ----------------------------------

extern "C" void kernel_launch(void* const* d_in, const int* in_sizes, int n_in,
                              void* d_out, int out_size, void* d_ws, size_t ws_size,
                              hipStream_t stream) {
  const float* x     = (const float*)d_in[0];
  const void*  ei    = d_in[1];
  const float* W1    = (const float*)d_in[2];
  const float* asrc1 = (const float*)d_in[3];
  const float* adst1 = (const float*)d_in[4];
  const float* b1    = (const float*)d_in[5];
  const float* W2    = (const float*)d_in[6];
  const float* asrc2 = (const float*)d_in[7];
  const float* adst2 = (const float*)d_in[8];
  const float* b2    = (const float*)d_in[9];
  const float* gamma = (const float*)d_in[10];
  const float* beta  = (const float*)d_in[11];
  float* out = (float*)d_out;

  const int E0 = in_sizes[1] / 2;       // 800000 raw edges
  const int ET = E0 + NNODES;           // + self loops

  // ws layout (< 89.7 MB). Overlays (R16-verified):
  //   z      [0,51.2M)      agg2in..gemm2ln (25K x 1024 bf16, 2 passes)
  //   pairs  [25.6M,32.4M)  binscatter..csrbin (inside h1 region, dead then)
  //   h1     [25.6M,51.2M)  gemm1..agg1
  //   xb     [51.2M,64M)    conv..gemm1
  //   out1   [51.2M,76.8M)  agg1..agg2in
  //   alpha  [76.8M,83.6M)  per-layer reuse (fp16 half4) — NO pairs overlay
  char* w = (char*)d_ws;
  bf16_t* z      = (bf16_t*)(w + 0);          // 25000*1024*2 = 51.2 MB
  int2*   pairs  = (int2*)(w + 25600000);     // 850000*8 = 6.8 MB (pre-gemm1)
  bf16_t* h1     = (bf16_t*)(w + 25600000);
  bf16_t* xb     = (bf16_t*)(w + 51200000);
  bf16_t* out1   = (bf16_t*)(w + 51200000);
  ushort* alpha  = (ushort*)(w + 76800000);   // 850000*8 = 6.8 MB
  float* es    = (float*)(w + 83600000);      // 800 KB
  float* ed    = (float*)(w + 84400000);      // 800 KB
  bf16_t* Wt1    = (bf16_t*)(w + 85200000);   // 64 KB
  bf16_t* Wt2s   = (bf16_t*)(w + 85300000);   // 128*1024*2 = 256 KB
  float* ws2   = (float*)(w + 85564000);      // 4 KB
  float* wd2   = (float*)(w + 85570000);      // 4 KB
  int* rowptr   = (int*)(w + 85600000);       // 50001 ints
  int* binStart = (int*)(w + 85800064);       // 197 ints
  int* binTotal = (int*)(w + 85801000);       // 196 ints
  int* blockBin = (int*)(w + 85802000);       // 196*256 ints = 200.7 KB
  int* col      = (int*)(w + 86200192);       // 3.4 MB

  // ---- prep: bf16 conversions + layer-2 weight prep ----
  convert_x_kernel<<<(NNODES * 128 / 4 + 255) / 256, 256, 0, stream>>>(x, xb,
                                                                       NNODES * 128 / 4);
  transpose_w_kernel<128, 256><<<256, 128, 0, stream>>>(W1, Wt1);
  proj2_kernel<<<4, 256, 0, stream>>>(W2, asrc2, adst2, ws2, wd2);
  wstack_kernel<<<128, 1024, 0, stream>>>(W2, Wt2s);

  // ---- CSR build (two-level counting sort; mode detection folded in) ----
  const int CHUNK = (ET + ABLOCKS - 1) / ABLOCKS;
  binhist_kernel<<<ABLOCKS, 256, 0, stream>>>(ei, blockBin, E0, ET, CHUNK);
  binscanA_kernel<<<NBINS, ABLOCKS, 0, stream>>>(blockBin, binTotal);
  binscanB_kernel<<<1, 256, 0, stream>>>(binTotal, binStart);
  binscatter_kernel<<<ABLOCKS, 256, 0, stream>>>(ei, blockBin, binStart, pairs,
                                                 E0, ET, CHUNK);
  csrbin_kernel<<<NBINS, 256, 0, stream>>>(pairs, binStart, rowptr, col);

  const int MB = (NNODES + 63) / 64;       // 782
  const int NODE_BLOCKS = (NNODES + 3) / 4;             // 64-lane-per-node
  const int NODE_BLOCKS16 = (NNODES * 16 + 255) / 256;  // 16-lane-per-node

  // ---- layer 1 (scores fused into gemm1 epilogue) ----
  gemm1s_kernel<<<dim3(MB, 4), 256, 0, stream>>>(xb, Wt1, h1, asrc1, adst1,
                                                 es, ed, NNODES);
  alpha_kernel<<<NODE_BLOCKS16, 256, 0, stream>>>(es, ed, rowptr, col, alpha);
  aggregate1_kernel<<<NODE_BLOCKS, 256, 0, stream>>>(h1, alpha, rowptr, col, b1,
                                                     out1, ws2, wd2, es, ed);

  // ---- layer 2 (scores fused into aggregate1 epilogue) ----
  alpha_kernel<<<NODE_BLOCKS16, 256, 0, stream>>>(es, ed, rowptr, col, alpha);

  const int HALF = NNODES / 2;                       // 25000
  const int AB = (HALF * 64 + 255) / 256;            // 6250 blocks (4 nodes each)
  const int GB = (HALF + 63) / 64;                   // 391 blocks
  agg2in_kernel<<<AB, 256, 0, stream>>>(out1, alpha, rowptr, col, z, 0, HALF);
  gemm2ln_kernel<<<GB, 256, 0, stream>>>(z, Wt2s, b2, gamma, beta, out, 0, HALF);
  agg2in_kernel<<<AB, 256, 0, stream>>>(out1, alpha, rowptr, col, z, HALF, NNODES);
  gemm2ln_kernel<<<GB, 256, 0, stream>>>(z, Wt2s, b2, gamma, beta, out, HALF, HALF);
}

// Round 11
// 362.911 us; speedup vs baseline: 1.1991x; 1.0749x over previous
//
#include <hip/hip_runtime.h>
#include <hip/hip_fp16.h>
#include <cstdint>
#include <cstddef>

// ---------------------------------------------------------------------------
// GAT x2 + LayerNorm on MI355X.
// R16: counting-sort CSR (434us). R19: score fusion (408us).
// R21: alpha16 + detect fold (verified 390us).
// R22 (this round): int8 gather payloads — h1 and out1 stored as int8 with
//   per-group scales (groupmax/127), scales FOLDED into alpha:
//     layer1: alpha' = alpha * scl1[src][head]   (gather group == head)
//     layer2: alpha' = alpha * scl2[src]         (per-row scale)
//   Gather loops keep the R19-proven 4-deep MLP shape; bytes halve
//   (512B -> 256B per edge row). Quant err ~0.4%/group; absmax budget ok.
// ---------------------------------------------------------------------------

constexpr int NNODES = 50000;
constexpr int NBINS = (NNODES + 255) >> 8;   // 196 coarse bins (256 nodes each)
constexpr int ABLOCKS = 256;                 // binning grid

typedef unsigned short bf16_t;
typedef __attribute__((ext_vector_type(8))) short bf16x8;
typedef __attribute__((ext_vector_type(4))) float f32x4;

__device__ __forceinline__ float bf2f(bf16_t b) {
  return __uint_as_float(((unsigned int)b) << 16);
}
__device__ __forceinline__ bf16_t f2bf(float f) {
  unsigned int u = __float_as_uint(f);
  u += 0x7fffu + ((u >> 16) & 1u);   // round to nearest even
  return (bf16_t)(u >> 16);
}
__device__ __forceinline__ float4 bf4_to_f4(ushort4 v) {
  return make_float4(bf2f(v.x), bf2f(v.y), bf2f(v.z), bf2f(v.w));
}
__device__ __forceinline__ ushort4 f4_to_bf4(float4 v) {
  return make_ushort4(f2bf(v.x), f2bf(v.y), f2bf(v.z), f2bf(v.w));
}
__device__ __forceinline__ ushort f2h(float f) {
  __half h = __float2half_rn(f);
  return *(ushort*)&h;
}
__device__ __forceinline__ float h2f(ushort u) {
  __half h; *(ushort*)&h = u;
  return __half2float(h);
}
__device__ __forceinline__ float lrelu(float x) { return x > 0.f ? x : 0.2f * x; }
__device__ __forceinline__ int clampi(int v, int lo, int hi) {
  return v < lo ? lo : (v > hi ? hi : v);
}
__device__ __forceinline__ int load_edge(const void* ei, int mode, int idx) {
  if (mode) return (int)((const long long*)ei)[idx];
  return ((const int*)ei)[idx];
}
__device__ __forceinline__ float4 c4_to_f4(char4 v) {
  return make_float4((float)v.x, (float)v.y, (float)v.z, (float)v.w);
}

// Per-block edge-dtype detection (deterministic, same 256 samples per block).
__device__ __forceinline__ int block_detect_mode(const int* ei32, int* nz_sm) {
  if (threadIdx.x == 0) *nz_sm = 0;
  __syncthreads();
  if (threadIdx.x < 256 && ei32[2 * threadIdx.x + 1] != 0) atomicAdd(nz_sm, 1);
  __syncthreads();
  return (*nz_sm == 0) ? 1 : 0;
}

// ------------------------------ prep kernels -------------------------------

__global__ void convert_x_kernel(const float* __restrict__ x, bf16_t* __restrict__ xb,
                                 int n4) {
  int i = blockIdx.x * blockDim.x + threadIdx.x;
  if (i >= n4) return;
  float4 v = *(const float4*)(x + 4 * (size_t)i);
  *(ushort4*)(xb + 4 * (size_t)i) = f4_to_bf4(v);
}

template <int K, int NC>
__global__ void transpose_w_kernel(const float* __restrict__ W, bf16_t* __restrict__ Wt) {
  int n = blockIdx.x;
  int k = threadIdx.x;
  Wt[(size_t)n * K + k] = f2bf(W[(size_t)k * NC + n]);
}

// ws2[h,k] = sum_c W2[k, h*128+c] * a_src2[h,c]   (and wd2 with a_dst2)
__global__ void proj2_kernel(const float* __restrict__ W2,
                             const float* __restrict__ asrc2,
                             const float* __restrict__ adst2,
                             float* __restrict__ ws2, float* __restrict__ wd2) {
  int h = blockIdx.x;      // 0..3
  int k = threadIdx.x;     // 0..255
  const float* wrow = W2 + (size_t)k * 512 + h * 128;
  const float* as = asrc2 + h * 128;
  const float* ad = adst2 + h * 128;
  float s = 0.f, d = 0.f;
  for (int c = 0; c < 128; ++c) { s += wrow[c] * as[c]; d += wrow[c] * ad[c]; }
  ws2[h * 256 + k] = s;
  wd2[h * 256 + k] = d;
}

// Wt2s[c][h*256+k] = W2[k, h*128+c] * 0.25  (stacked weight, transposed, bf16)
__global__ __launch_bounds__(1024) void wstack_kernel(const float* __restrict__ W2,
                                                      bf16_t* __restrict__ Wt2s) {
  int c = blockIdx.x;      // 0..127
  int t = threadIdx.x;     // 0..1023 : h = t>>8, k = t&255
  int h = t >> 8, k = t & 255;
  Wt2s[(size_t)c * 1024 + t] = f2bf(W2[(size_t)k * 512 + h * 128 + c] * 0.25f);
}

// --------------------- CSR build: two-level counting sort ------------------
__global__ __launch_bounds__(256) void binhist_kernel(
    const void* __restrict__ ei, int* __restrict__ blockBin,
    int e0, int et, int chunk) {
  __shared__ int h[NBINS];
  __shared__ int nzsm;
  int mode = block_detect_mode((const int*)ei, &nzsm);
  int t = threadIdx.x, blk = blockIdx.x;
  for (int i = t; i < NBINS; i += 256) h[i] = 0;
  __syncthreads();
  int lo = blk * chunk, hi = min(et, lo + chunk);
  for (int e = lo + t; e < hi; e += 256) {
    int dst = (e < e0) ? load_edge(ei, mode, e0 + e) : (e - e0);
    dst = clampi(dst, 0, NNODES - 1);
    atomicAdd(&h[dst >> 8], 1);
  }
  __syncthreads();
  for (int i = t; i < NBINS; i += 256) blockBin[i * ABLOCKS + blk] = h[i];
}

__global__ __launch_bounds__(ABLOCKS) void binscanA_kernel(int* __restrict__ blockBin,
                                                           int* __restrict__ binTotal) {
  __shared__ int sm[ABLOCKS];
  int b = blockIdx.x, t = threadIdx.x;
  int orig = blockBin[b * ABLOCKS + t];
  sm[t] = orig;
  __syncthreads();
  for (int off = 1; off < ABLOCKS; off <<= 1) {
    int u = (t >= off) ? sm[t - off] : 0;
    __syncthreads();
    sm[t] += u;
    __syncthreads();
  }
  blockBin[b * ABLOCKS + t] = sm[t] - orig;
  if (t == ABLOCKS - 1) binTotal[b] = sm[ABLOCKS - 1];
}

__global__ __launch_bounds__(256) void binscanB_kernel(const int* __restrict__ binTotal,
                                                       int* __restrict__ binStart) {
  __shared__ int sm[256];
  int t = threadIdx.x;
  int orig = (t < NBINS) ? binTotal[t] : 0;
  sm[t] = orig;
  __syncthreads();
  for (int off = 1; off < 256; off <<= 1) {
    int u = (t >= off) ? sm[t - off] : 0;
    __syncthreads();
    sm[t] += u;
    __syncthreads();
  }
  if (t < NBINS) binStart[t] = sm[t] - orig;
  if (t == 255) binStart[NBINS] = sm[255];
}

__global__ __launch_bounds__(256) void binscatter_kernel(
    const void* __restrict__ ei, const int* __restrict__ blockBin,
    const int* __restrict__ binStart, int2* __restrict__ pairs,
    int e0, int et, int chunk) {
  __shared__ int cur[NBINS];
  __shared__ int nzsm;
  int mode = block_detect_mode((const int*)ei, &nzsm);
  int t = threadIdx.x, blk = blockIdx.x;
  for (int i = t; i < NBINS; i += 256)
    cur[i] = binStart[i] + blockBin[i * ABLOCKS + blk];
  __syncthreads();
  int lo = blk * chunk, hi = min(et, lo + chunk);
  for (int e = lo + t; e < hi; e += 256) {
    int src, dst;
    if (e < e0) { src = load_edge(ei, mode, e); dst = load_edge(ei, mode, e0 + e); }
    else        { src = dst = e - e0; }
    src = clampi(src, 0, NNODES - 1);
    dst = clampi(dst, 0, NNODES - 1);
    int p = atomicAdd(&cur[dst >> 8], 1);
    pairs[p] = make_int2(src, dst);
  }
}

// B: per-bin CSR finalize — defensive clamp keeps LDS safe.
__global__ __launch_bounds__(256) void csrbin_kernel(const int2* __restrict__ pairs,
                                                     const int* __restrict__ binStart,
                                                     int* __restrict__ rowptr,
                                                     int* __restrict__ col) {
  __shared__ int cnt[256];
  __shared__ int sc[256];
  int b = blockIdx.x, t = threadIdx.x;
  int node0 = b << 8;
  int es = binStart[b], ee = binStart[b + 1];
  cnt[t] = 0;
  __syncthreads();
  for (int p = es + t; p < ee; p += 256) {
    int2 pr = pairs[p];
    int d = clampi(pr.y - node0, 0, 255);
    atomicAdd(&cnt[d], 1);
  }
  __syncthreads();
  int orig = cnt[t];
  sc[t] = orig;
  __syncthreads();
  for (int off = 1; off < 256; off <<= 1) {
    int u = (t >= off) ? sc[t - off] : 0;
    __syncthreads();
    sc[t] += u;
    __syncthreads();
  }
  int excl = sc[t] - orig;
  if (node0 + t < NNODES) rowptr[node0 + t] = es + excl;
  if (b == NBINS - 1 && t == 0) rowptr[NNODES] = ee;
  cnt[t] = excl;
  __syncthreads();
  for (int p = es + t; p < ee; p += 256) {
    int2 pr = pairs[p];
    int d = clampi(pr.y - node0, 0, 255);
    int pos = atomicAdd(&cnt[d], 1);
    col[es + pos] = pr.x;
  }
}

// --------------- MFMA GEMM (layer 1): scores + int8 h1 quant ---------------
// C int8 per-(row,head) scale: scl1[row*4+hd] = groupmax/127.
__global__ __launch_bounds__(256) void gemm1s_kernel(
    const bf16_t* __restrict__ A, const bf16_t* __restrict__ Wt,
    char* __restrict__ h1q, float* __restrict__ scl1,
    const float* __restrict__ asrc, const float* __restrict__ adst,
    float* __restrict__ es, float* __restrict__ ed, int M) {
  __shared__ __align__(16) ushort As[64 * 40];
  __shared__ __align__(16) ushort Bs[64 * 40];
  const int t    = threadIdx.x;
  const int wv   = t >> 6;
  const int lane = t & 63;
  const int m    = lane & 15;
  const int quad = lane >> 4;
  const int bm = blockIdx.x * 64, bn = blockIdx.y * 64;
  const int srow = t & 63;
  const int sk8  = t >> 6;

  f32x4 acc0 = {0.f, 0.f, 0.f, 0.f};
  f32x4 acc1 = {0.f, 0.f, 0.f, 0.f};
  f32x4 acc2 = {0.f, 0.f, 0.f, 0.f};
  f32x4 acc3 = {0.f, 0.f, 0.f, 0.f};

  for (int k0 = 0; k0 < 128; k0 += 32) {
    int ga = clampi(bm + srow, 0, M - 1);
    float4 av = *(const float4*)(A + (size_t)ga * 128 + k0 + sk8 * 8);
    *(float4*)(&As[srow * 40 + sk8 * 8]) = av;
    float4 bv = *(const float4*)(Wt + (size_t)(bn + srow) * 128 + k0 + sk8 * 8);
    *(float4*)(&Bs[srow * 40 + sk8 * 8]) = bv;
    __syncthreads();

    bf16x8 af = *(const bf16x8*)(&As[(wv * 16 + m) * 40 + quad * 8]);
    bf16x8 b0 = *(const bf16x8*)(&Bs[(0 * 16 + m) * 40 + quad * 8]);
    bf16x8 b1 = *(const bf16x8*)(&Bs[(1 * 16 + m) * 40 + quad * 8]);
    bf16x8 b2 = *(const bf16x8*)(&Bs[(2 * 16 + m) * 40 + quad * 8]);
    bf16x8 b3 = *(const bf16x8*)(&Bs[(3 * 16 + m) * 40 + quad * 8]);
    acc0 = __builtin_amdgcn_mfma_f32_16x16x32_bf16(af, b0, acc0, 0, 0, 0);
    acc1 = __builtin_amdgcn_mfma_f32_16x16x32_bf16(af, b1, acc1, 0, 0, 0);
    acc2 = __builtin_amdgcn_mfma_f32_16x16x32_bf16(af, b2, acc2, 0, 0, 0);
    acc3 = __builtin_amdgcn_mfma_f32_16x16x32_bf16(af, b3, acc3, 0, 0, 0);
    __syncthreads();
  }

  float as0 = asrc[bn +  0 + m], as1 = asrc[bn + 16 + m];
  float as2 = asrc[bn + 32 + m], as3 = asrc[bn + 48 + m];
  float ad0 = adst[bn +  0 + m], ad1 = adst[bn + 16 + m];
  float ad2 = adst[bn + 32 + m], ad3 = adst[bn + 48 + m];
  const int hd = bn >> 6;

#pragma unroll
  for (int r = 0; r < 4; ++r) {
    int row = bm + wv * 16 + quad * 4 + r;
    float ps = acc0[r] * as0 + acc1[r] * as1 + acc2[r] * as2 + acc3[r] * as3;
    float pd = acc0[r] * ad0 + acc1[r] * ad1 + acc2[r] * ad2 + acc3[r] * ad3;
    float mx = fmaxf(fmaxf(fabsf(acc0[r]), fabsf(acc1[r])),
                     fmaxf(fabsf(acc2[r]), fabsf(acc3[r])));
    for (int mm = 1; mm < 16; mm <<= 1) {
      ps += __shfl_xor(ps, mm);
      pd += __shfl_xor(pd, mm);
      mx = fmaxf(mx, __shfl_xor(mx, mm));
    }
    float inv = mx > 0.f ? 127.f / mx : 0.f;
    if (row < M) {
      size_t base = (size_t)row * 256 + bn;
      h1q[base +  0 + m] = (char)__float2int_rn(acc0[r] * inv);
      h1q[base + 16 + m] = (char)__float2int_rn(acc1[r] * inv);
      h1q[base + 32 + m] = (char)__float2int_rn(acc2[r] * inv);
      h1q[base + 48 + m] = (char)__float2int_rn(acc3[r] * inv);
      if (m == 0) {
        scl1[row * 4 + hd] = mx * (1.f / 127.f);
        es[row * 4 + hd] = ps;
        ed[row * 4 + hd] = pd;
      }
    }
  }
}

// --------------------------- alpha precompute (fp16) -----------------------
// 16 lanes per node (4 nodes/wave). SMODE 0: fold float4 per-src scale
// (layer 1, per-head). SMODE 1: fold scalar per-src scale (layer 2, per-row).
template <int SMODE>
__global__ __launch_bounds__(256) void alpha_kernel(
    const float* __restrict__ es, const float* __restrict__ ed,
    const int* __restrict__ rowptr, const int* __restrict__ col,
    const float* __restrict__ scales, ushort* __restrict__ alpha) {
  int node = (blockIdx.x * blockDim.x + threadIdx.x) >> 4;
  if (node >= NNODES) return;
  int l16 = threadIdx.x & 15;
  int beg = rowptr[node], end = rowptr[node + 1];
  float4 edv = *(const float4*)(ed + node * 4);
  float4 l = make_float4(0.f, 0.f, 0.f, 0.f);
  for (int p = beg + l16; p < end; p += 16) {
    int s = col[p];
    float4 e = *(const float4*)(es + s * 4);
    l.x += __expf(lrelu(e.x + edv.x));
    l.y += __expf(lrelu(e.y + edv.y));
    l.z += __expf(lrelu(e.z + edv.z));
    l.w += __expf(lrelu(e.w + edv.w));
  }
  for (int off = 1; off < 16; off <<= 1) {
    l.x += __shfl_xor(l.x, off);
    l.y += __shfl_xor(l.y, off);
    l.z += __shfl_xor(l.z, off);
    l.w += __shfl_xor(l.w, off);
  }
  float4 il = make_float4(1.f / (l.x + 1e-16f), 1.f / (l.y + 1e-16f),
                          1.f / (l.z + 1e-16f), 1.f / (l.w + 1e-16f));
  for (int p = beg + l16; p < end; p += 16) {
    int s = col[p];
    float4 e = *(const float4*)(es + s * 4);
    float sx, sy, sz, sw;
    if (SMODE == 0) {
      float4 sc = *(const float4*)(scales + s * 4);
      sx = sc.x; sy = sc.y; sz = sc.z; sw = sc.w;
    } else {
      float sc = scales[s];
      sx = sc; sy = sc; sz = sc; sw = sc;
    }
    ushort4 a;
    a.x = f2h(__expf(lrelu(e.x + edv.x)) * il.x * sx);
    a.y = f2h(__expf(lrelu(e.y + edv.y)) * il.y * sy);
    a.z = f2h(__expf(lrelu(e.z + edv.z)) * il.z * sz);
    a.w = f2h(__expf(lrelu(e.w + edv.w)) * il.w * sw);
    *(ushort4*)(alpha + (size_t)p * 4) = a;
  }
}

// ------------------------------- aggregation -------------------------------
// layer 1: wave per node; lane holds 4 channels at 4*lane (head = lane>>4);
// int8 gather (4B/lane), scale pre-folded into alpha. Unroll x4.
// Epilogue: bias+relu, fused layer-2 scores, per-row int8 quant of out1.
__global__ __launch_bounds__(256) void aggregate1_kernel(
    const char* __restrict__ h1q, const ushort* __restrict__ alpha,
    const int* __restrict__ rowptr, const int* __restrict__ col,
    const float* __restrict__ b1, char* __restrict__ out1q,
    float* __restrict__ scl2,
    const float* __restrict__ ws2, const float* __restrict__ wd2,
    float* __restrict__ es2, float* __restrict__ ed2) {
  int node = (blockIdx.x * blockDim.x + threadIdx.x) >> 6;
  if (node >= NNODES) return;
  int lane = threadIdx.x & 63;
  int head = lane >> 4;
  int beg = rowptr[node], end = rowptr[node + 1];
  float4 acc = make_float4(0.f, 0.f, 0.f, 0.f);
  int j = beg;
  for (; j + 4 <= end; j += 4) {
    int s0 = col[j], s1 = col[j + 1], s2 = col[j + 2], s3 = col[j + 3];
    ushort u0 = alpha[(size_t)(j + 0) * 4 + head];
    ushort u1 = alpha[(size_t)(j + 1) * 4 + head];
    ushort u2 = alpha[(size_t)(j + 2) * 4 + head];
    ushort u3 = alpha[(size_t)(j + 3) * 4 + head];
    char4 r0 = *(const char4*)(h1q + (size_t)s0 * 256 + 4 * lane);
    char4 r1 = *(const char4*)(h1q + (size_t)s1 * 256 + 4 * lane);
    char4 r2 = *(const char4*)(h1q + (size_t)s2 * 256 + 4 * lane);
    char4 r3 = *(const char4*)(h1q + (size_t)s3 * 256 + 4 * lane);
    float a0 = h2f(u0), a1 = h2f(u1), a2 = h2f(u2), a3 = h2f(u3);
    float4 v0 = c4_to_f4(r0), v1 = c4_to_f4(r1);
    float4 v2 = c4_to_f4(r2), v3 = c4_to_f4(r3);
    acc.x += a0 * v0.x + a1 * v1.x + a2 * v2.x + a3 * v3.x;
    acc.y += a0 * v0.y + a1 * v1.y + a2 * v2.y + a3 * v3.y;
    acc.z += a0 * v0.z + a1 * v1.z + a2 * v2.z + a3 * v3.z;
    acc.w += a0 * v0.w + a1 * v1.w + a2 * v2.w + a3 * v3.w;
  }
  for (; j < end; ++j) {
    int s0 = col[j];
    float a0 = h2f(alpha[(size_t)j * 4 + head]);
    float4 v0 = c4_to_f4(*(const char4*)(h1q + (size_t)s0 * 256 + 4 * lane));
    acc.x += a0 * v0.x;
    acc.y += a0 * v0.y;
    acc.z += a0 * v0.z;
    acc.w += a0 * v0.w;
  }
  float4 bb = *(const float4*)(b1 + 4 * lane);
  float4 o;
  o.x = fmaxf(acc.x + bb.x, 0.f);
  o.y = fmaxf(acc.y + bb.y, 0.f);
  o.z = fmaxf(acc.z + bb.z, 0.f);
  o.w = fmaxf(acc.w + bb.w, 0.f);

  // fused layer-2 scores from exact fp32 o
  float s2[4], d2[4];
#pragma unroll
  for (int hh = 0; hh < 4; ++hh) {
    float4 wv = *(const float4*)(ws2 + hh * 256 + 4 * lane);
    float4 dv = *(const float4*)(wd2 + hh * 256 + 4 * lane);
    s2[hh] = o.x * wv.x + o.y * wv.y + o.z * wv.z + o.w * wv.w;
    d2[hh] = o.x * dv.x + o.y * dv.y + o.z * dv.z + o.w * dv.w;
  }
  for (int mm = 1; mm < 64; mm <<= 1) {
#pragma unroll
    for (int hh = 0; hh < 4; ++hh) {
      s2[hh] += __shfl_xor(s2[hh], mm);
      d2[hh] += __shfl_xor(d2[hh], mm);
    }
  }

  // per-row int8 quantization of out1 (o >= 0)
  float mx = fmaxf(fmaxf(o.x, o.y), fmaxf(o.z, o.w));
  for (int mm = 1; mm < 64; mm <<= 1) mx = fmaxf(mx, __shfl_xor(mx, mm));
  float inv = mx > 0.f ? 127.f / mx : 0.f;
  char4 oq;
  oq.x = (char)__float2int_rn(o.x * inv);
  oq.y = (char)__float2int_rn(o.y * inv);
  oq.z = (char)__float2int_rn(o.z * inv);
  oq.w = (char)__float2int_rn(o.w * inv);
  *(char4*)(out1q + (size_t)node * 256 + 4 * lane) = oq;
  if (lane == 0) {
    scl2[node] = mx * (1.f / 127.f);
#pragma unroll
    for (int hh = 0; hh < 4; ++hh) {
      es2[node * 4 + hh] = s2[hh];
      ed2[node * 4 + hh] = d2[hh];
    }
  }
}

// layer 2 aggregation in INPUT space: z[dst, h*256+c] = sum_e alpha'[e,h]*out1q[src,c]
// (scale pre-folded into alpha'). int8 gather, unroll x4, acc[4 heads][4 ch].
__device__ __forceinline__ void fma4h(float (&acc)[4][4], ushort4 q, float4 v) {
  float f0 = h2f(q.x), f1 = h2f(q.y), f2 = h2f(q.z), f3 = h2f(q.w);
  acc[0][0] += f0 * v.x; acc[0][1] += f0 * v.y; acc[0][2] += f0 * v.z; acc[0][3] += f0 * v.w;
  acc[1][0] += f1 * v.x; acc[1][1] += f1 * v.y; acc[1][2] += f1 * v.z; acc[1][3] += f1 * v.w;
  acc[2][0] += f2 * v.x; acc[2][1] += f2 * v.y; acc[2][2] += f2 * v.z; acc[2][3] += f2 * v.w;
  acc[3][0] += f3 * v.x; acc[3][1] += f3 * v.y; acc[3][2] += f3 * v.z; acc[3][3] += f3 * v.w;
}

__global__ __launch_bounds__(256) void agg2in_kernel(
    const char* __restrict__ out1q, const ushort* __restrict__ alpha,
    const int* __restrict__ rowptr, const int* __restrict__ col,
    bf16_t* __restrict__ z, int n0, int n1) {
  int node = n0 + ((blockIdx.x * blockDim.x + threadIdx.x) >> 6);
  if (node >= n1) return;
  int lane = threadIdx.x & 63;
  int beg = rowptr[node], end = rowptr[node + 1];
  float acc[4][4] = {{0.f,0.f,0.f,0.f},{0.f,0.f,0.f,0.f},
                     {0.f,0.f,0.f,0.f},{0.f,0.f,0.f,0.f}};
  int j = beg;
  for (; j + 4 <= end; j += 4) {
    int s0 = col[j], s1 = col[j + 1], s2 = col[j + 2], s3 = col[j + 3];
    ushort4 q0 = *(const ushort4*)(alpha + (size_t)(j + 0) * 4);
    ushort4 q1 = *(const ushort4*)(alpha + (size_t)(j + 1) * 4);
    ushort4 q2 = *(const ushort4*)(alpha + (size_t)(j + 2) * 4);
    ushort4 q3 = *(const ushort4*)(alpha + (size_t)(j + 3) * 4);
    char4 r0 = *(const char4*)(out1q + (size_t)s0 * 256 + 4 * lane);
    char4 r1 = *(const char4*)(out1q + (size_t)s1 * 256 + 4 * lane);
    char4 r2 = *(const char4*)(out1q + (size_t)s2 * 256 + 4 * lane);
    char4 r3 = *(const char4*)(out1q + (size_t)s3 * 256 + 4 * lane);
    fma4h(acc, q0, c4_to_f4(r0));
    fma4h(acc, q1, c4_to_f4(r1));
    fma4h(acc, q2, c4_to_f4(r2));
    fma4h(acc, q3, c4_to_f4(r3));
  }
  for (; j < end; ++j) {
    int s0 = col[j];
    ushort4 q0 = *(const ushort4*)(alpha + (size_t)j * 4);
    char4 r0 = *(const char4*)(out1q + (size_t)s0 * 256 + 4 * lane);
    fma4h(acc, q0, c4_to_f4(r0));
  }
  bf16_t* zr = z + (size_t)(node - n0) * 1024 + 4 * lane;
#pragma unroll
  for (int h = 0; h < 4; ++h) {
    *(ushort4*)(zr + h * 256) =
        f4_to_bf4(make_float4(acc[h][0], acc[h][1], acc[h][2], acc[h][3]));
  }
}

// GEMM [M,1024] @ Wt2s[128][1024] -> out[M,128] with +b2 and fused LayerNorm.
__global__ __launch_bounds__(256) void gemm2ln_kernel(
    const bf16_t* __restrict__ Z, const bf16_t* __restrict__ Wt2s,
    const float* __restrict__ b2, const float* __restrict__ gamma,
    const float* __restrict__ beta, float* __restrict__ out, int n0, int M) {
  __shared__ __align__(16) ushort As[64 * 40];
  __shared__ __align__(16) ushort Bs[128 * 40];
  const int t    = threadIdx.x;
  const int wv   = t >> 6;
  const int lane = t & 63;
  const int m    = lane & 15;
  const int quad = lane >> 4;
  const int bm   = blockIdx.x * 64;

  f32x4 c0 = {0.f,0.f,0.f,0.f}, c1 = c0, c2 = c0, c3 = c0;
  f32x4 c4 = c0, c5 = c0, c6 = c0, c7 = c0;

  const int arow = t & 63, ak8 = t >> 6;
  for (int k0 = 0; k0 < 1024; k0 += 32) {
    int ga = clampi(bm + arow, 0, M - 1);
    *(float4*)(&As[arow * 40 + ak8 * 8]) =
        *(const float4*)(Z + (size_t)ga * 1024 + k0 + ak8 * 8);
    {
      int q = t;          // chunk: row = q>>2 (0..127), k8 = q&3
      *(float4*)(&Bs[(q >> 2) * 40 + (q & 3) * 8]) =
          *(const float4*)(Wt2s + (size_t)(q >> 2) * 1024 + k0 + (q & 3) * 8);
      q = t + 256;
      *(float4*)(&Bs[(q >> 2) * 40 + (q & 3) * 8]) =
          *(const float4*)(Wt2s + (size_t)(q >> 2) * 1024 + k0 + (q & 3) * 8);
    }
    __syncthreads();

    bf16x8 af = *(const bf16x8*)(&As[(wv * 16 + m) * 40 + quad * 8]);
    bf16x8 b0 = *(const bf16x8*)(&Bs[(0 * 16 + m) * 40 + quad * 8]);
    bf16x8 b1 = *(const bf16x8*)(&Bs[(1 * 16 + m) * 40 + quad * 8]);
    bf16x8 b2f = *(const bf16x8*)(&Bs[(2 * 16 + m) * 40 + quad * 8]);
    bf16x8 b3 = *(const bf16x8*)(&Bs[(3 * 16 + m) * 40 + quad * 8]);
    bf16x8 b4 = *(const bf16x8*)(&Bs[(4 * 16 + m) * 40 + quad * 8]);
    bf16x8 b5 = *(const bf16x8*)(&Bs[(5 * 16 + m) * 40 + quad * 8]);
    bf16x8 b6 = *(const bf16x8*)(&Bs[(6 * 16 + m) * 40 + quad * 8]);
    bf16x8 b7 = *(const bf16x8*)(&Bs[(7 * 16 + m) * 40 + quad * 8]);
    c0 = __builtin_amdgcn_mfma_f32_16x16x32_bf16(af, b0, c0, 0, 0, 0);
    c1 = __builtin_amdgcn_mfma_f32_16x16x32_bf16(af, b1, c1, 0, 0, 0);
    c2 = __builtin_amdgcn_mfma_f32_16x16x32_bf16(af, b2f, c2, 0, 0, 0);
    c3 = __builtin_amdgcn_mfma_f32_16x16x32_bf16(af, b3, c3, 0, 0, 0);
    c4 = __builtin_amdgcn_mfma_f32_16x16x32_bf16(af, b4, c4, 0, 0, 0);
    c5 = __builtin_amdgcn_mfma_f32_16x16x32_bf16(af, b5, c5, 0, 0, 0);
    c6 = __builtin_amdgcn_mfma_f32_16x16x32_bf16(af, b6, c6, 0, 0, 0);
    c7 = __builtin_amdgcn_mfma_f32_16x16x32_bf16(af, b7, c7, 0, 0, 0);
    __syncthreads();
  }

  // ----- fused +b2 and LayerNorm over the 128-wide row -----
  float b2v[8], gv[8], btv[8];
#pragma unroll
  for (int n = 0; n < 8; ++n) {
    int c = n * 16 + m;
    b2v[n] = b2[c]; gv[n] = gamma[c]; btv[n] = beta[c];
  }
#pragma unroll
  for (int r = 0; r < 4; ++r) {
    float v0 = c0[r] + b2v[0], v1 = c1[r] + b2v[1];
    float v2 = c2[r] + b2v[2], v3 = c3[r] + b2v[3];
    float v4 = c4[r] + b2v[4], v5 = c5[r] + b2v[5];
    float v6 = c6[r] + b2v[6], v7 = c7[r] + b2v[7];
    float tsum = v0 + v1 + v2 + v3 + v4 + v5 + v6 + v7;
    tsum += __shfl_xor(tsum, 1); tsum += __shfl_xor(tsum, 2);
    tsum += __shfl_xor(tsum, 4); tsum += __shfl_xor(tsum, 8);
    float mu = tsum * (1.f / 128.f);
    float d0 = v0 - mu, d1 = v1 - mu, d2 = v2 - mu, d3 = v3 - mu;
    float d4 = v4 - mu, d5 = v5 - mu, d6 = v6 - mu, d7 = v7 - mu;
    float vq = d0*d0 + d1*d1 + d2*d2 + d3*d3 + d4*d4 + d5*d5 + d6*d6 + d7*d7;
    vq += __shfl_xor(vq, 1); vq += __shfl_xor(vq, 2);
    vq += __shfl_xor(vq, 4); vq += __shfl_xor(vq, 8);
    float rinv = rsqrtf(vq * (1.f / 128.f) + 1e-5f);
    int row = bm + wv * 16 + quad * 4 + r;
    if (row < M) {
      float* orow = out + (size_t)(n0 + row) * 128;
      orow[0 * 16 + m] = d0 * rinv * gv[0] + btv[0];
      orow[1 * 16 + m] = d1 * rinv * gv[1] + btv[1];
      orow[2 * 16 + m] = d2 * rinv * gv[2] + btv[2];
      orow[3 * 16 + m] = d3 * rinv * gv[3] + btv[3];
      orow[4 * 16 + m] = d4 * rinv * gv[4] + btv[4];
      orow[5 * 16 + m] = d5 * rinv * gv[5] + btv[5];
      orow[6 * 16 + m] = d6 * rinv * gv[6] + btv[6];
      orow[7 * 16 + m] = d7 * rinv * gv[7] + btv[7];
    }
  }
}

// ------------------------------- launcher ----------------------------------

extern "C" void kernel_launch(void* const* d_in, const int* in_sizes, int n_in,
                              void* d_out, int out_size, void* d_ws, size_t ws_size,
                              hipStream_t stream) {
  const float* x     = (const float*)d_in[0];
  const void*  ei    = d_in[1];
  const float* W1    = (const float*)d_in[2];
  const float* asrc1 = (const float*)d_in[3];
  const float* adst1 = (const float*)d_in[4];
  const float* b1    = (const float*)d_in[5];
  const float* W2    = (const float*)d_in[6];
  const float* asrc2 = (const float*)d_in[7];
  const float* adst2 = (const float*)d_in[8];
  const float* b2    = (const float*)d_in[9];
  const float* gamma = (const float*)d_in[10];
  const float* beta  = (const float*)d_in[11];
  float* out = (float*)d_out;

  const int E0 = in_sizes[1] / 2;       // 800000 raw edges
  const int ET = E0 + NNODES;           // + self loops

  // ws layout (< 89.7 MB). Overlays:
  //   z      [0,51.2M)      agg2in..gemm2ln (25K x 1024 bf16, 2 passes)
  //   pairs  [25.6M,32.4M)  binscatter..csrbin (dead before gemm1s)
  //   h1q    [25.6M,38.4M)  gemm1s..aggregate1 (int8)
  //   scl1   [38.4M,39.2M)  gemm1s..alpha1
  //   xb     [51.2M,64M)    conv..gemm1s
  //   out1q  [51.2M,64M)    aggregate1..agg2in (int8, overlays dead xb)
  //   scl2   [64.1M,64.3M)  aggregate1..alpha2
  //   alpha  [76.8M,83.6M)  per-layer reuse (fp16 half4)
  char* w = (char*)d_ws;
  bf16_t* z      = (bf16_t*)(w + 0);          // 25000*1024*2 = 51.2 MB
  int2*   pairs  = (int2*)(w + 25600000);     // 850000*8 = 6.8 MB (pre-gemm1s)
  char*   h1q    = (char*)(w + 25600000);     // 50000*256 = 12.8 MB
  float*  scl1   = (float*)(w + 38400000);    // 50000*4*4 = 800 KB
  bf16_t* xb     = (bf16_t*)(w + 51200000);   // 12.8 MB
  char*   out1q  = (char*)(w + 51200000);     // 12.8 MB (overlays dead xb)
  float*  scl2   = (float*)(w + 64100000);    // 200 KB
  ushort* alpha  = (ushort*)(w + 76800000);   // 850000*8 = 6.8 MB
  float* es    = (float*)(w + 83600000);      // 800 KB
  float* ed    = (float*)(w + 84400000);      // 800 KB
  bf16_t* Wt1    = (bf16_t*)(w + 85200000);   // 64 KB
  bf16_t* Wt2s   = (bf16_t*)(w + 85300000);   // 128*1024*2 = 256 KB
  float* ws2   = (float*)(w + 85564000);      // 4 KB
  float* wd2   = (float*)(w + 85570000);      // 4 KB
  int* rowptr   = (int*)(w + 85600000);       // 50001 ints
  int* binStart = (int*)(w + 85800064);       // 197 ints
  int* binTotal = (int*)(w + 85801000);       // 196 ints
  int* blockBin = (int*)(w + 85802000);       // 196*256 ints = 200.7 KB
  int* col      = (int*)(w + 86200192);       // 3.4 MB

  // ---- prep: bf16 conversions + layer-2 weight prep ----
  convert_x_kernel<<<(NNODES * 128 / 4 + 255) / 256, 256, 0, stream>>>(x, xb,
                                                                       NNODES * 128 / 4);
  transpose_w_kernel<128, 256><<<256, 128, 0, stream>>>(W1, Wt1);
  proj2_kernel<<<4, 256, 0, stream>>>(W2, asrc2, adst2, ws2, wd2);
  wstack_kernel<<<128, 1024, 0, stream>>>(W2, Wt2s);

  // ---- CSR build (two-level counting sort; mode detection folded in) ----
  const int CHUNK = (ET + ABLOCKS - 1) / ABLOCKS;
  binhist_kernel<<<ABLOCKS, 256, 0, stream>>>(ei, blockBin, E0, ET, CHUNK);
  binscanA_kernel<<<NBINS, ABLOCKS, 0, stream>>>(blockBin, binTotal);
  binscanB_kernel<<<1, 256, 0, stream>>>(binTotal, binStart);
  binscatter_kernel<<<ABLOCKS, 256, 0, stream>>>(ei, blockBin, binStart, pairs,
                                                 E0, ET, CHUNK);
  csrbin_kernel<<<NBINS, 256, 0, stream>>>(pairs, binStart, rowptr, col);

  const int MB = (NNODES + 63) / 64;       // 782
  const int NODE_BLOCKS = (NNODES + 3) / 4;             // 64-lane-per-node
  const int NODE_BLOCKS16 = (NNODES * 16 + 255) / 256;  // 16-lane-per-node

  // ---- layer 1 (scores + int8 quant fused into gemm1s epilogue) ----
  gemm1s_kernel<<<dim3(MB, 4), 256, 0, stream>>>(xb, Wt1, h1q, scl1,
                                                 asrc1, adst1, es, ed, NNODES);
  alpha_kernel<0><<<NODE_BLOCKS16, 256, 0, stream>>>(es, ed, rowptr, col,
                                                     scl1, alpha);
  aggregate1_kernel<<<NODE_BLOCKS, 256, 0, stream>>>(h1q, alpha, rowptr, col, b1,
                                                     out1q, scl2, ws2, wd2, es, ed);

  // ---- layer 2 (scores fused into aggregate1 epilogue) ----
  alpha_kernel<1><<<NODE_BLOCKS16, 256, 0, stream>>>(es, ed, rowptr, col,
                                                     scl2, alpha);

  const int HALF = NNODES / 2;                       // 25000
  const int AB = (HALF * 64 + 255) / 256;            // 6250 blocks (4 nodes each)
  const int GB = (HALF + 63) / 64;                   // 391 blocks
  agg2in_kernel<<<AB, 256, 0, stream>>>(out1q, alpha, rowptr, col, z, 0, HALF);
  gemm2ln_kernel<<<GB, 256, 0, stream>>>(z, Wt2s, b2, gamma, beta, out, 0, HALF);
  agg2in_kernel<<<AB, 256, 0, stream>>>(out1q, alpha, rowptr, col, z, HALF, NNODES);
  gemm2ln_kernel<<<GB, 256, 0, stream>>>(z, Wt2s, b2, gamma, beta, out, HALF, HALF);
}

// Round 12
// 358.974 us; speedup vs baseline: 1.2122x; 1.0110x over previous
//
#include <hip/hip_runtime.h>
#include <hip/hip_fp16.h>
#include <cstdint>
#include <cstddef>

// ---------------------------------------------------------------------------
// GAT x2 + LayerNorm on MI355X.
// R16: counting-sort CSR (434us). R19: score fusion (408us).
// R21: alpha16 + detect fold (390us). R22: int8 gather payloads (362.9us,
//   absmax 0.031) — but signed unpack (bfe+cvt_i32) made aggregate1
//   VALU-bound (61%).
// R23 (this round): unsigned payloads for HW ubyte converts.
//   - h1q: biased uint8 (q+128); exact correction acc -= 128*sum(alpha').
//   - out1q: pure unsigned [0,255] (out1>=0 post-ReLU); no correction.
//   - wprep: merge transpose_w/proj2/wstack into one dispatch.
// ---------------------------------------------------------------------------

constexpr int NNODES = 50000;
constexpr int NBINS = (NNODES + 255) >> 8;   // 196 coarse bins (256 nodes each)
constexpr int ABLOCKS = 256;                 // binning grid

typedef unsigned short bf16_t;
typedef unsigned char u8_t;
typedef __attribute__((ext_vector_type(8))) short bf16x8;
typedef __attribute__((ext_vector_type(4))) float f32x4;

__device__ __forceinline__ float bf2f(bf16_t b) {
  return __uint_as_float(((unsigned int)b) << 16);
}
__device__ __forceinline__ bf16_t f2bf(float f) {
  unsigned int u = __float_as_uint(f);
  u += 0x7fffu + ((u >> 16) & 1u);   // round to nearest even
  return (bf16_t)(u >> 16);
}
__device__ __forceinline__ float4 bf4_to_f4(ushort4 v) {
  return make_float4(bf2f(v.x), bf2f(v.y), bf2f(v.z), bf2f(v.w));
}
__device__ __forceinline__ ushort4 f4_to_bf4(float4 v) {
  return make_ushort4(f2bf(v.x), f2bf(v.y), f2bf(v.z), f2bf(v.w));
}
__device__ __forceinline__ ushort f2h(float f) {
  __half h = __float2half_rn(f);
  return *(ushort*)&h;
}
__device__ __forceinline__ float h2f(ushort u) {
  __half h; *(ushort*)&h = u;
  return __half2float(h);
}
__device__ __forceinline__ float lrelu(float x) { return x > 0.f ? x : 0.2f * x; }
__device__ __forceinline__ int clampi(int v, int lo, int hi) {
  return v < lo ? lo : (v > hi ? hi : v);
}
__device__ __forceinline__ int load_edge(const void* ei, int mode, int idx) {
  if (mode) return (int)((const long long*)ei)[idx];
  return ((const int*)ei)[idx];
}
// unsigned-byte unpack — pattern-matched to v_cvt_f32_ubyte0..3
__device__ __forceinline__ float4 u32_to_f4(unsigned int r) {
  return make_float4((float)(r & 0xFFu), (float)((r >> 8) & 0xFFu),
                     (float)((r >> 16) & 0xFFu), (float)(r >> 24));
}

// Per-block edge-dtype detection (deterministic, same 256 samples per block).
__device__ __forceinline__ int block_detect_mode(const int* ei32, int* nz_sm) {
  if (threadIdx.x == 0) *nz_sm = 0;
  __syncthreads();
  if (threadIdx.x < 256 && ei32[2 * threadIdx.x + 1] != 0) atomicAdd(nz_sm, 1);
  __syncthreads();
  return (*nz_sm == 0) ? 1 : 0;
}

// ------------------------------ prep kernels -------------------------------

__global__ void convert_x_kernel(const float* __restrict__ x, bf16_t* __restrict__ xb,
                                 int n4) {
  int i = blockIdx.x * blockDim.x + threadIdx.x;
  if (i >= n4) return;
  float4 v = *(const float4*)(x + 4 * (size_t)i);
  *(ushort4*)(xb + 4 * (size_t)i) = f4_to_bf4(v);
}

// Merged weight prep: blocks [0,256) -> Wt1 transpose; [256,260) -> proj2;
// [260,388) -> Wt2s stack.
__global__ __launch_bounds__(256) void wprep_kernel(
    const float* __restrict__ W1, const float* __restrict__ W2,
    const float* __restrict__ asrc2, const float* __restrict__ adst2,
    bf16_t* __restrict__ Wt1, float* __restrict__ ws2, float* __restrict__ wd2,
    bf16_t* __restrict__ Wt2s) {
  int b = blockIdx.x;
  int t = threadIdx.x;
  if (b < 256) {
    if (t < 128) Wt1[(size_t)b * 128 + t] = f2bf(W1[(size_t)t * 256 + b]);
  } else if (b < 260) {
    int h = b - 256;
    const float* wrow = W2 + (size_t)t * 512 + h * 128;
    const float* as = asrc2 + h * 128;
    const float* ad = adst2 + h * 128;
    float s = 0.f, d = 0.f;
    for (int c = 0; c < 128; ++c) { s += wrow[c] * as[c]; d += wrow[c] * ad[c]; }
    ws2[h * 256 + t] = s;
    wd2[h * 256 + t] = d;
  } else {
    int c = b - 260;   // 0..127
#pragma unroll
    for (int i = 0; i < 4; ++i) {
      int tt = t + 256 * i;          // 0..1023 : h = tt>>8, k = tt&255
      int h = tt >> 8, k = tt & 255;
      Wt2s[(size_t)c * 1024 + tt] = f2bf(W2[(size_t)k * 512 + h * 128 + c] * 0.25f);
    }
  }
}

// --------------------- CSR build: two-level counting sort ------------------
__global__ __launch_bounds__(256) void binhist_kernel(
    const void* __restrict__ ei, int* __restrict__ blockBin,
    int e0, int et, int chunk) {
  __shared__ int h[NBINS];
  __shared__ int nzsm;
  int mode = block_detect_mode((const int*)ei, &nzsm);
  int t = threadIdx.x, blk = blockIdx.x;
  for (int i = t; i < NBINS; i += 256) h[i] = 0;
  __syncthreads();
  int lo = blk * chunk, hi = min(et, lo + chunk);
  for (int e = lo + t; e < hi; e += 256) {
    int dst = (e < e0) ? load_edge(ei, mode, e0 + e) : (e - e0);
    dst = clampi(dst, 0, NNODES - 1);
    atomicAdd(&h[dst >> 8], 1);
  }
  __syncthreads();
  for (int i = t; i < NBINS; i += 256) blockBin[i * ABLOCKS + blk] = h[i];
}

__global__ __launch_bounds__(ABLOCKS) void binscanA_kernel(int* __restrict__ blockBin,
                                                           int* __restrict__ binTotal) {
  __shared__ int sm[ABLOCKS];
  int b = blockIdx.x, t = threadIdx.x;
  int orig = blockBin[b * ABLOCKS + t];
  sm[t] = orig;
  __syncthreads();
  for (int off = 1; off < ABLOCKS; off <<= 1) {
    int u = (t >= off) ? sm[t - off] : 0;
    __syncthreads();
    sm[t] += u;
    __syncthreads();
  }
  blockBin[b * ABLOCKS + t] = sm[t] - orig;
  if (t == ABLOCKS - 1) binTotal[b] = sm[ABLOCKS - 1];
}

__global__ __launch_bounds__(256) void binscanB_kernel(const int* __restrict__ binTotal,
                                                       int* __restrict__ binStart) {
  __shared__ int sm[256];
  int t = threadIdx.x;
  int orig = (t < NBINS) ? binTotal[t] : 0;
  sm[t] = orig;
  __syncthreads();
  for (int off = 1; off < 256; off <<= 1) {
    int u = (t >= off) ? sm[t - off] : 0;
    __syncthreads();
    sm[t] += u;
    __syncthreads();
  }
  if (t < NBINS) binStart[t] = sm[t] - orig;
  if (t == 255) binStart[NBINS] = sm[255];
}

__global__ __launch_bounds__(256) void binscatter_kernel(
    const void* __restrict__ ei, const int* __restrict__ blockBin,
    const int* __restrict__ binStart, int2* __restrict__ pairs,
    int e0, int et, int chunk) {
  __shared__ int cur[NBINS];
  __shared__ int nzsm;
  int mode = block_detect_mode((const int*)ei, &nzsm);
  int t = threadIdx.x, blk = blockIdx.x;
  for (int i = t; i < NBINS; i += 256)
    cur[i] = binStart[i] + blockBin[i * ABLOCKS + blk];
  __syncthreads();
  int lo = blk * chunk, hi = min(et, lo + chunk);
  for (int e = lo + t; e < hi; e += 256) {
    int src, dst;
    if (e < e0) { src = load_edge(ei, mode, e); dst = load_edge(ei, mode, e0 + e); }
    else        { src = dst = e - e0; }
    src = clampi(src, 0, NNODES - 1);
    dst = clampi(dst, 0, NNODES - 1);
    int p = atomicAdd(&cur[dst >> 8], 1);
    pairs[p] = make_int2(src, dst);
  }
}

// B: per-bin CSR finalize — defensive clamp keeps LDS safe.
__global__ __launch_bounds__(256) void csrbin_kernel(const int2* __restrict__ pairs,
                                                     const int* __restrict__ binStart,
                                                     int* __restrict__ rowptr,
                                                     int* __restrict__ col) {
  __shared__ int cnt[256];
  __shared__ int sc[256];
  int b = blockIdx.x, t = threadIdx.x;
  int node0 = b << 8;
  int es = binStart[b], ee = binStart[b + 1];
  cnt[t] = 0;
  __syncthreads();
  for (int p = es + t; p < ee; p += 256) {
    int2 pr = pairs[p];
    int d = clampi(pr.y - node0, 0, 255);
    atomicAdd(&cnt[d], 1);
  }
  __syncthreads();
  int orig = cnt[t];
  sc[t] = orig;
  __syncthreads();
  for (int off = 1; off < 256; off <<= 1) {
    int u = (t >= off) ? sc[t - off] : 0;
    __syncthreads();
    sc[t] += u;
    __syncthreads();
  }
  int excl = sc[t] - orig;
  if (node0 + t < NNODES) rowptr[node0 + t] = es + excl;
  if (b == NBINS - 1 && t == 0) rowptr[NNODES] = ee;
  cnt[t] = excl;
  __syncthreads();
  for (int p = es + t; p < ee; p += 256) {
    int2 pr = pairs[p];
    int d = clampi(pr.y - node0, 0, 255);
    int pos = atomicAdd(&cnt[d], 1);
    col[es + pos] = pr.x;
  }
}

// --------------- MFMA GEMM (layer 1): scores + biased-uint8 quant ----------
// h1q[c] = round(h1[c]/scl) + 128 (uint8); scl1[row*4+hd] = groupmax/127.
__global__ __launch_bounds__(256) void gemm1s_kernel(
    const bf16_t* __restrict__ A, const bf16_t* __restrict__ Wt,
    u8_t* __restrict__ h1q, float* __restrict__ scl1,
    const float* __restrict__ asrc, const float* __restrict__ adst,
    float* __restrict__ es, float* __restrict__ ed, int M) {
  __shared__ __align__(16) ushort As[64 * 40];
  __shared__ __align__(16) ushort Bs[64 * 40];
  const int t    = threadIdx.x;
  const int wv   = t >> 6;
  const int lane = t & 63;
  const int m    = lane & 15;
  const int quad = lane >> 4;
  const int bm = blockIdx.x * 64, bn = blockIdx.y * 64;
  const int srow = t & 63;
  const int sk8  = t >> 6;

  f32x4 acc0 = {0.f, 0.f, 0.f, 0.f};
  f32x4 acc1 = {0.f, 0.f, 0.f, 0.f};
  f32x4 acc2 = {0.f, 0.f, 0.f, 0.f};
  f32x4 acc3 = {0.f, 0.f, 0.f, 0.f};

  for (int k0 = 0; k0 < 128; k0 += 32) {
    int ga = clampi(bm + srow, 0, M - 1);
    float4 av = *(const float4*)(A + (size_t)ga * 128 + k0 + sk8 * 8);
    *(float4*)(&As[srow * 40 + sk8 * 8]) = av;
    float4 bv = *(const float4*)(Wt + (size_t)(bn + srow) * 128 + k0 + sk8 * 8);
    *(float4*)(&Bs[srow * 40 + sk8 * 8]) = bv;
    __syncthreads();

    bf16x8 af = *(const bf16x8*)(&As[(wv * 16 + m) * 40 + quad * 8]);
    bf16x8 b0 = *(const bf16x8*)(&Bs[(0 * 16 + m) * 40 + quad * 8]);
    bf16x8 b1 = *(const bf16x8*)(&Bs[(1 * 16 + m) * 40 + quad * 8]);
    bf16x8 b2 = *(const bf16x8*)(&Bs[(2 * 16 + m) * 40 + quad * 8]);
    bf16x8 b3 = *(const bf16x8*)(&Bs[(3 * 16 + m) * 40 + quad * 8]);
    acc0 = __builtin_amdgcn_mfma_f32_16x16x32_bf16(af, b0, acc0, 0, 0, 0);
    acc1 = __builtin_amdgcn_mfma_f32_16x16x32_bf16(af, b1, acc1, 0, 0, 0);
    acc2 = __builtin_amdgcn_mfma_f32_16x16x32_bf16(af, b2, acc2, 0, 0, 0);
    acc3 = __builtin_amdgcn_mfma_f32_16x16x32_bf16(af, b3, acc3, 0, 0, 0);
    __syncthreads();
  }

  float as0 = asrc[bn +  0 + m], as1 = asrc[bn + 16 + m];
  float as2 = asrc[bn + 32 + m], as3 = asrc[bn + 48 + m];
  float ad0 = adst[bn +  0 + m], ad1 = adst[bn + 16 + m];
  float ad2 = adst[bn + 32 + m], ad3 = adst[bn + 48 + m];
  const int hd = bn >> 6;

#pragma unroll
  for (int r = 0; r < 4; ++r) {
    int row = bm + wv * 16 + quad * 4 + r;
    float ps = acc0[r] * as0 + acc1[r] * as1 + acc2[r] * as2 + acc3[r] * as3;
    float pd = acc0[r] * ad0 + acc1[r] * ad1 + acc2[r] * ad2 + acc3[r] * ad3;
    float mx = fmaxf(fmaxf(fabsf(acc0[r]), fabsf(acc1[r])),
                     fmaxf(fabsf(acc2[r]), fabsf(acc3[r])));
    for (int mm = 1; mm < 16; mm <<= 1) {
      ps += __shfl_xor(ps, mm);
      pd += __shfl_xor(pd, mm);
      mx = fmaxf(mx, __shfl_xor(mx, mm));
    }
    float inv = mx > 0.f ? 127.f / mx : 0.f;
    if (row < M) {
      size_t base = (size_t)row * 256 + bn;
      h1q[base +  0 + m] = (u8_t)clampi(__float2int_rn(acc0[r] * inv) + 128, 0, 255);
      h1q[base + 16 + m] = (u8_t)clampi(__float2int_rn(acc1[r] * inv) + 128, 0, 255);
      h1q[base + 32 + m] = (u8_t)clampi(__float2int_rn(acc2[r] * inv) + 128, 0, 255);
      h1q[base + 48 + m] = (u8_t)clampi(__float2int_rn(acc3[r] * inv) + 128, 0, 255);
      if (m == 0) {
        scl1[row * 4 + hd] = mx * (1.f / 127.f);
        es[row * 4 + hd] = ps;
        ed[row * 4 + hd] = pd;
      }
    }
  }
}

// --------------------------- alpha precompute (fp16) -----------------------
// 16 lanes per node (4 nodes/wave). SMODE 0: fold float4 per-src scale
// (layer 1, per-head). SMODE 1: fold scalar per-src scale (layer 2, per-row).
template <int SMODE>
__global__ __launch_bounds__(256) void alpha_kernel(
    const float* __restrict__ es, const float* __restrict__ ed,
    const int* __restrict__ rowptr, const int* __restrict__ col,
    const float* __restrict__ scales, ushort* __restrict__ alpha) {
  int node = (blockIdx.x * blockDim.x + threadIdx.x) >> 4;
  if (node >= NNODES) return;
  int l16 = threadIdx.x & 15;
  int beg = rowptr[node], end = rowptr[node + 1];
  float4 edv = *(const float4*)(ed + node * 4);
  float4 l = make_float4(0.f, 0.f, 0.f, 0.f);
  for (int p = beg + l16; p < end; p += 16) {
    int s = col[p];
    float4 e = *(const float4*)(es + s * 4);
    l.x += __expf(lrelu(e.x + edv.x));
    l.y += __expf(lrelu(e.y + edv.y));
    l.z += __expf(lrelu(e.z + edv.z));
    l.w += __expf(lrelu(e.w + edv.w));
  }
  for (int off = 1; off < 16; off <<= 1) {
    l.x += __shfl_xor(l.x, off);
    l.y += __shfl_xor(l.y, off);
    l.z += __shfl_xor(l.z, off);
    l.w += __shfl_xor(l.w, off);
  }
  float4 il = make_float4(1.f / (l.x + 1e-16f), 1.f / (l.y + 1e-16f),
                          1.f / (l.z + 1e-16f), 1.f / (l.w + 1e-16f));
  for (int p = beg + l16; p < end; p += 16) {
    int s = col[p];
    float4 e = *(const float4*)(es + s * 4);
    float sx, sy, sz, sw;
    if (SMODE == 0) {
      float4 sc = *(const float4*)(scales + s * 4);
      sx = sc.x; sy = sc.y; sz = sc.z; sw = sc.w;
    } else {
      float sc = scales[s];
      sx = sc; sy = sc; sz = sc; sw = sc;
    }
    ushort4 a;
    a.x = f2h(__expf(lrelu(e.x + edv.x)) * il.x * sx);
    a.y = f2h(__expf(lrelu(e.y + edv.y)) * il.y * sy);
    a.z = f2h(__expf(lrelu(e.z + edv.z)) * il.z * sz);
    a.w = f2h(__expf(lrelu(e.w + edv.w)) * il.w * sw);
    *(ushort4*)(alpha + (size_t)p * 4) = a;
  }
}

// ------------------------------- aggregation -------------------------------
// layer 1: wave per node; lane holds 4 channels at 4*lane (head = lane>>4);
// biased-uint8 gather (4B/lane) with ubyte converts + exact -128*sum(alpha)
// correction. Unroll x4. Epilogue: bias+relu, fused layer-2 scores,
// per-row unsigned quant of out1 (out1 >= 0).
__global__ __launch_bounds__(256) void aggregate1_kernel(
    const u8_t* __restrict__ h1q, const ushort* __restrict__ alpha,
    const int* __restrict__ rowptr, const int* __restrict__ col,
    const float* __restrict__ b1, u8_t* __restrict__ out1q,
    float* __restrict__ scl2,
    const float* __restrict__ ws2, const float* __restrict__ wd2,
    float* __restrict__ es2, float* __restrict__ ed2) {
  int node = (blockIdx.x * blockDim.x + threadIdx.x) >> 6;
  if (node >= NNODES) return;
  int lane = threadIdx.x & 63;
  int head = lane >> 4;
  int beg = rowptr[node], end = rowptr[node + 1];
  float4 acc = make_float4(0.f, 0.f, 0.f, 0.f);
  float aSum = 0.f;
  int j = beg;
  for (; j + 4 <= end; j += 4) {
    int s0 = col[j], s1 = col[j + 1], s2 = col[j + 2], s3 = col[j + 3];
    ushort u0 = alpha[(size_t)(j + 0) * 4 + head];
    ushort u1 = alpha[(size_t)(j + 1) * 4 + head];
    ushort u2 = alpha[(size_t)(j + 2) * 4 + head];
    ushort u3 = alpha[(size_t)(j + 3) * 4 + head];
    unsigned int r0 = *(const unsigned int*)(h1q + (size_t)s0 * 256 + 4 * lane);
    unsigned int r1 = *(const unsigned int*)(h1q + (size_t)s1 * 256 + 4 * lane);
    unsigned int r2 = *(const unsigned int*)(h1q + (size_t)s2 * 256 + 4 * lane);
    unsigned int r3 = *(const unsigned int*)(h1q + (size_t)s3 * 256 + 4 * lane);
    float a0 = h2f(u0), a1 = h2f(u1), a2 = h2f(u2), a3 = h2f(u3);
    aSum += (a0 + a1) + (a2 + a3);
    float4 v0 = u32_to_f4(r0), v1 = u32_to_f4(r1);
    float4 v2 = u32_to_f4(r2), v3 = u32_to_f4(r3);
    acc.x += a0 * v0.x + a1 * v1.x + a2 * v2.x + a3 * v3.x;
    acc.y += a0 * v0.y + a1 * v1.y + a2 * v2.y + a3 * v3.y;
    acc.z += a0 * v0.z + a1 * v1.z + a2 * v2.z + a3 * v3.z;
    acc.w += a0 * v0.w + a1 * v1.w + a2 * v2.w + a3 * v3.w;
  }
  for (; j < end; ++j) {
    int s0 = col[j];
    float a0 = h2f(alpha[(size_t)j * 4 + head]);
    aSum += a0;
    float4 v0 = u32_to_f4(*(const unsigned int*)(h1q + (size_t)s0 * 256 + 4 * lane));
    acc.x += a0 * v0.x;
    acc.y += a0 * v0.y;
    acc.z += a0 * v0.z;
    acc.w += a0 * v0.w;
  }
  // exact bias correction: stored u = q + 128, sum(a*u) - 128*sum(a) = sum(a*q)
  float corr = 128.f * aSum;
  acc.x -= corr; acc.y -= corr; acc.z -= corr; acc.w -= corr;

  float4 bb = *(const float4*)(b1 + 4 * lane);
  float4 o;
  o.x = fmaxf(acc.x + bb.x, 0.f);
  o.y = fmaxf(acc.y + bb.y, 0.f);
  o.z = fmaxf(acc.z + bb.z, 0.f);
  o.w = fmaxf(acc.w + bb.w, 0.f);

  // fused layer-2 scores from exact fp32 o
  float s2[4], d2[4];
#pragma unroll
  for (int hh = 0; hh < 4; ++hh) {
    float4 wv = *(const float4*)(ws2 + hh * 256 + 4 * lane);
    float4 dv = *(const float4*)(wd2 + hh * 256 + 4 * lane);
    s2[hh] = o.x * wv.x + o.y * wv.y + o.z * wv.z + o.w * wv.w;
    d2[hh] = o.x * dv.x + o.y * dv.y + o.z * dv.z + o.w * dv.w;
  }
  for (int mm = 1; mm < 64; mm <<= 1) {
#pragma unroll
    for (int hh = 0; hh < 4; ++hh) {
      s2[hh] += __shfl_xor(s2[hh], mm);
      d2[hh] += __shfl_xor(d2[hh], mm);
    }
  }

  // per-row unsigned quantization of out1 (o >= 0): u = round(o*255/mx)
  float mx = fmaxf(fmaxf(o.x, o.y), fmaxf(o.z, o.w));
  for (int mm = 1; mm < 64; mm <<= 1) mx = fmaxf(mx, __shfl_xor(mx, mm));
  float inv = mx > 0.f ? 255.f / mx : 0.f;
  uchar4 oq;
  oq.x = (u8_t)clampi(__float2int_rn(o.x * inv), 0, 255);
  oq.y = (u8_t)clampi(__float2int_rn(o.y * inv), 0, 255);
  oq.z = (u8_t)clampi(__float2int_rn(o.z * inv), 0, 255);
  oq.w = (u8_t)clampi(__float2int_rn(o.w * inv), 0, 255);
  *(uchar4*)(out1q + (size_t)node * 256 + 4 * lane) = oq;
  if (lane == 0) {
    scl2[node] = mx * (1.f / 255.f);
#pragma unroll
    for (int hh = 0; hh < 4; ++hh) {
      es2[node * 4 + hh] = s2[hh];
      ed2[node * 4 + hh] = d2[hh];
    }
  }
}

// layer 2 aggregation in INPUT space: z[dst, h*256+c] = sum_e alpha'[e,h]*u[src,c]
// (scale pre-folded into alpha'; u unsigned, no correction needed).
__device__ __forceinline__ void fma4h(float (&acc)[4][4], ushort4 q, float4 v) {
  float f0 = h2f(q.x), f1 = h2f(q.y), f2 = h2f(q.z), f3 = h2f(q.w);
  acc[0][0] += f0 * v.x; acc[0][1] += f0 * v.y; acc[0][2] += f0 * v.z; acc[0][3] += f0 * v.w;
  acc[1][0] += f1 * v.x; acc[1][1] += f1 * v.y; acc[1][2] += f1 * v.z; acc[1][3] += f1 * v.w;
  acc[2][0] += f2 * v.x; acc[2][1] += f2 * v.y; acc[2][2] += f2 * v.z; acc[2][3] += f2 * v.w;
  acc[3][0] += f3 * v.x; acc[3][1] += f3 * v.y; acc[3][2] += f3 * v.z; acc[3][3] += f3 * v.w;
}

__global__ __launch_bounds__(256) void agg2in_kernel(
    const u8_t* __restrict__ out1q, const ushort* __restrict__ alpha,
    const int* __restrict__ rowptr, const int* __restrict__ col,
    bf16_t* __restrict__ z, int n0, int n1) {
  int node = n0 + ((blockIdx.x * blockDim.x + threadIdx.x) >> 6);
  if (node >= n1) return;
  int lane = threadIdx.x & 63;
  int beg = rowptr[node], end = rowptr[node + 1];
  float acc[4][4] = {{0.f,0.f,0.f,0.f},{0.f,0.f,0.f,0.f},
                     {0.f,0.f,0.f,0.f},{0.f,0.f,0.f,0.f}};
  int j = beg;
  for (; j + 4 <= end; j += 4) {
    int s0 = col[j], s1 = col[j + 1], s2 = col[j + 2], s3 = col[j + 3];
    ushort4 q0 = *(const ushort4*)(alpha + (size_t)(j + 0) * 4);
    ushort4 q1 = *(const ushort4*)(alpha + (size_t)(j + 1) * 4);
    ushort4 q2 = *(const ushort4*)(alpha + (size_t)(j + 2) * 4);
    ushort4 q3 = *(const ushort4*)(alpha + (size_t)(j + 3) * 4);
    unsigned int r0 = *(const unsigned int*)(out1q + (size_t)s0 * 256 + 4 * lane);
    unsigned int r1 = *(const unsigned int*)(out1q + (size_t)s1 * 256 + 4 * lane);
    unsigned int r2 = *(const unsigned int*)(out1q + (size_t)s2 * 256 + 4 * lane);
    unsigned int r3 = *(const unsigned int*)(out1q + (size_t)s3 * 256 + 4 * lane);
    fma4h(acc, q0, u32_to_f4(r0));
    fma4h(acc, q1, u32_to_f4(r1));
    fma4h(acc, q2, u32_to_f4(r2));
    fma4h(acc, q3, u32_to_f4(r3));
  }
  for (; j < end; ++j) {
    int s0 = col[j];
    ushort4 q0 = *(const ushort4*)(alpha + (size_t)j * 4);
    unsigned int r0 = *(const unsigned int*)(out1q + (size_t)s0 * 256 + 4 * lane);
    fma4h(acc, q0, u32_to_f4(r0));
  }
  bf16_t* zr = z + (size_t)(node - n0) * 1024 + 4 * lane;
#pragma unroll
  for (int h = 0; h < 4; ++h) {
    *(ushort4*)(zr + h * 256) =
        f4_to_bf4(make_float4(acc[h][0], acc[h][1], acc[h][2], acc[h][3]));
  }
}

// GEMM [M,1024] @ Wt2s[128][1024] -> out[M,128] with +b2 and fused LayerNorm.
__global__ __launch_bounds__(256) void gemm2ln_kernel(
    const bf16_t* __restrict__ Z, const bf16_t* __restrict__ Wt2s,
    const float* __restrict__ b2, const float* __restrict__ gamma,
    const float* __restrict__ beta, float* __restrict__ out, int n0, int M) {
  __shared__ __align__(16) ushort As[64 * 40];
  __shared__ __align__(16) ushort Bs[128 * 40];
  const int t    = threadIdx.x;
  const int wv   = t >> 6;
  const int lane = t & 63;
  const int m    = lane & 15;
  const int quad = lane >> 4;
  const int bm   = blockIdx.x * 64;

  f32x4 c0 = {0.f,0.f,0.f,0.f}, c1 = c0, c2 = c0, c3 = c0;
  f32x4 c4 = c0, c5 = c0, c6 = c0, c7 = c0;

  const int arow = t & 63, ak8 = t >> 6;
  for (int k0 = 0; k0 < 1024; k0 += 32) {
    int ga = clampi(bm + arow, 0, M - 1);
    *(float4*)(&As[arow * 40 + ak8 * 8]) =
        *(const float4*)(Z + (size_t)ga * 1024 + k0 + ak8 * 8);
    {
      int q = t;          // chunk: row = q>>2 (0..127), k8 = q&3
      *(float4*)(&Bs[(q >> 2) * 40 + (q & 3) * 8]) =
          *(const float4*)(Wt2s + (size_t)(q >> 2) * 1024 + k0 + (q & 3) * 8);
      q = t + 256;
      *(float4*)(&Bs[(q >> 2) * 40 + (q & 3) * 8]) =
          *(const float4*)(Wt2s + (size_t)(q >> 2) * 1024 + k0 + (q & 3) * 8);
    }
    __syncthreads();

    bf16x8 af = *(const bf16x8*)(&As[(wv * 16 + m) * 40 + quad * 8]);
    bf16x8 b0 = *(const bf16x8*)(&Bs[(0 * 16 + m) * 40 + quad * 8]);
    bf16x8 b1 = *(const bf16x8*)(&Bs[(1 * 16 + m) * 40 + quad * 8]);
    bf16x8 b2f = *(const bf16x8*)(&Bs[(2 * 16 + m) * 40 + quad * 8]);
    bf16x8 b3 = *(const bf16x8*)(&Bs[(3 * 16 + m) * 40 + quad * 8]);
    bf16x8 b4 = *(const bf16x8*)(&Bs[(4 * 16 + m) * 40 + quad * 8]);
    bf16x8 b5 = *(const bf16x8*)(&Bs[(5 * 16 + m) * 40 + quad * 8]);
    bf16x8 b6 = *(const bf16x8*)(&Bs[(6 * 16 + m) * 40 + quad * 8]);
    bf16x8 b7 = *(const bf16x8*)(&Bs[(7 * 16 + m) * 40 + quad * 8]);
    c0 = __builtin_amdgcn_mfma_f32_16x16x32_bf16(af, b0, c0, 0, 0, 0);
    c1 = __builtin_amdgcn_mfma_f32_16x16x32_bf16(af, b1, c1, 0, 0, 0);
    c2 = __builtin_amdgcn_mfma_f32_16x16x32_bf16(af, b2f, c2, 0, 0, 0);
    c3 = __builtin_amdgcn_mfma_f32_16x16x32_bf16(af, b3, c3, 0, 0, 0);
    c4 = __builtin_amdgcn_mfma_f32_16x16x32_bf16(af, b4, c4, 0, 0, 0);
    c5 = __builtin_amdgcn_mfma_f32_16x16x32_bf16(af, b5, c5, 0, 0, 0);
    c6 = __builtin_amdgcn_mfma_f32_16x16x32_bf16(af, b6, c6, 0, 0, 0);
    c7 = __builtin_amdgcn_mfma_f32_16x16x32_bf16(af, b7, c7, 0, 0, 0);
    __syncthreads();
  }

  // ----- fused +b2 and LayerNorm over the 128-wide row -----
  float b2v[8], gv[8], btv[8];
#pragma unroll
  for (int n = 0; n < 8; ++n) {
    int c = n * 16 + m;
    b2v[n] = b2[c]; gv[n] = gamma[c]; btv[n] = beta[c];
  }
#pragma unroll
  for (int r = 0; r < 4; ++r) {
    float v0 = c0[r] + b2v[0], v1 = c1[r] + b2v[1];
    float v2 = c2[r] + b2v[2], v3 = c3[r] + b2v[3];
    float v4 = c4[r] + b2v[4], v5 = c5[r] + b2v[5];
    float v6 = c6[r] + b2v[6], v7 = c7[r] + b2v[7];
    float tsum = v0 + v1 + v2 + v3 + v4 + v5 + v6 + v7;
    tsum += __shfl_xor(tsum, 1); tsum += __shfl_xor(tsum, 2);
    tsum += __shfl_xor(tsum, 4); tsum += __shfl_xor(tsum, 8);
    float mu = tsum * (1.f / 128.f);
    float d0 = v0 - mu, d1 = v1 - mu, d2 = v2 - mu, d3 = v3 - mu;
    float d4 = v4 - mu, d5 = v5 - mu, d6 = v6 - mu, d7 = v7 - mu;
    float vq = d0*d0 + d1*d1 + d2*d2 + d3*d3 + d4*d4 + d5*d5 + d6*d6 + d7*d7;
    vq += __shfl_xor(vq, 1); vq += __shfl_xor(vq, 2);
    vq += __shfl_xor(vq, 4); vq += __shfl_xor(vq, 8);
    float rinv = rsqrtf(vq * (1.f / 128.f) + 1e-5f);
    int row = bm + wv * 16 + quad * 4 + r;
    if (row < M) {
      float* orow = out + (size_t)(n0 + row) * 128;
      orow[0 * 16 + m] = d0 * rinv * gv[0] + btv[0];
      orow[1 * 16 + m] = d1 * rinv * gv[1] + btv[1];
      orow[2 * 16 + m] = d2 * rinv * gv[2] + btv[2];
      orow[3 * 16 + m] = d3 * rinv * gv[3] + btv[3];
      orow[4 * 16 + m] = d4 * rinv * gv[4] + btv[4];
      orow[5 * 16 + m] = d5 * rinv * gv[5] + btv[5];
      orow[6 * 16 + m] = d6 * rinv * gv[6] + btv[6];
      orow[7 * 16 + m] = d7 * rinv * gv[7] + btv[7];
    }
  }
}

// ------------------------------- launcher ----------------------------------

extern "C" void kernel_launch(void* const* d_in, const int* in_sizes, int n_in,
                              void* d_out, int out_size, void* d_ws, size_t ws_size,
                              hipStream_t stream) {
  const float* x     = (const float*)d_in[0];
  const void*  ei    = d_in[1];
  const float* W1    = (const float*)d_in[2];
  const float* asrc1 = (const float*)d_in[3];
  const float* adst1 = (const float*)d_in[4];
  const float* b1    = (const float*)d_in[5];
  const float* W2    = (const float*)d_in[6];
  const float* asrc2 = (const float*)d_in[7];
  const float* adst2 = (const float*)d_in[8];
  const float* b2    = (const float*)d_in[9];
  const float* gamma = (const float*)d_in[10];
  const float* beta  = (const float*)d_in[11];
  float* out = (float*)d_out;

  const int E0 = in_sizes[1] / 2;       // 800000 raw edges
  const int ET = E0 + NNODES;           // + self loops

  // ws layout (< 89.7 MB). Overlays:
  //   z      [0,51.2M)      agg2in..gemm2ln (25K x 1024 bf16, 2 passes)
  //   pairs  [25.6M,32.4M)  binscatter..csrbin (dead before gemm1s)
  //   h1q    [25.6M,38.4M)  gemm1s..aggregate1 (uint8 biased)
  //   scl1   [38.4M,39.2M)  gemm1s..alpha1
  //   xb     [51.2M,64M)    conv..gemm1s
  //   out1q  [51.2M,64M)    aggregate1..agg2in (uint8, overlays dead xb)
  //   scl2   [64.1M,64.3M)  aggregate1..alpha2
  //   alpha  [76.8M,83.6M)  per-layer reuse (fp16 half4)
  char* w = (char*)d_ws;
  bf16_t* z      = (bf16_t*)(w + 0);          // 25000*1024*2 = 51.2 MB
  int2*   pairs  = (int2*)(w + 25600000);     // 850000*8 = 6.8 MB (pre-gemm1s)
  u8_t*   h1q    = (u8_t*)(w + 25600000);     // 50000*256 = 12.8 MB
  float*  scl1   = (float*)(w + 38400000);    // 50000*4*4 = 800 KB
  bf16_t* xb     = (bf16_t*)(w + 51200000);   // 12.8 MB
  u8_t*   out1q  = (u8_t*)(w + 51200000);     // 12.8 MB (overlays dead xb)
  float*  scl2   = (float*)(w + 64100000);    // 200 KB
  ushort* alpha  = (ushort*)(w + 76800000);   // 850000*8 = 6.8 MB
  float* es    = (float*)(w + 83600000);      // 800 KB
  float* ed    = (float*)(w + 84400000);      // 800 KB
  bf16_t* Wt1    = (bf16_t*)(w + 85200000);   // 64 KB
  bf16_t* Wt2s   = (bf16_t*)(w + 85300000);   // 128*1024*2 = 256 KB
  float* ws2   = (float*)(w + 85564000);      // 4 KB
  float* wd2   = (float*)(w + 85570000);      // 4 KB
  int* rowptr   = (int*)(w + 85600000);       // 50001 ints
  int* binStart = (int*)(w + 85800064);       // 197 ints
  int* binTotal = (int*)(w + 85801000);       // 196 ints
  int* blockBin = (int*)(w + 85802000);       // 196*256 ints = 200.7 KB
  int* col      = (int*)(w + 86200192);       // 3.4 MB

  // ---- prep: bf16 conversion + merged weight prep ----
  convert_x_kernel<<<(NNODES * 128 / 4 + 255) / 256, 256, 0, stream>>>(x, xb,
                                                                       NNODES * 128 / 4);
  wprep_kernel<<<388, 256, 0, stream>>>(W1, W2, asrc2, adst2, Wt1, ws2, wd2, Wt2s);

  // ---- CSR build (two-level counting sort; mode detection folded in) ----
  const int CHUNK = (ET + ABLOCKS - 1) / ABLOCKS;
  binhist_kernel<<<ABLOCKS, 256, 0, stream>>>(ei, blockBin, E0, ET, CHUNK);
  binscanA_kernel<<<NBINS, ABLOCKS, 0, stream>>>(blockBin, binTotal);
  binscanB_kernel<<<1, 256, 0, stream>>>(binTotal, binStart);
  binscatter_kernel<<<ABLOCKS, 256, 0, stream>>>(ei, blockBin, binStart, pairs,
                                                 E0, ET, CHUNK);
  csrbin_kernel<<<NBINS, 256, 0, stream>>>(pairs, binStart, rowptr, col);

  const int MB = (NNODES + 63) / 64;       // 782
  const int NODE_BLOCKS = (NNODES + 3) / 4;             // 64-lane-per-node
  const int NODE_BLOCKS16 = (NNODES * 16 + 255) / 256;  // 16-lane-per-node

  // ---- layer 1 (scores + biased-uint8 quant fused into gemm1s) ----
  gemm1s_kernel<<<dim3(MB, 4), 256, 0, stream>>>(xb, Wt1, h1q, scl1,
                                                 asrc1, adst1, es, ed, NNODES);
  alpha_kernel<0><<<NODE_BLOCKS16, 256, 0, stream>>>(es, ed, rowptr, col,
                                                     scl1, alpha);
  aggregate1_kernel<<<NODE_BLOCKS, 256, 0, stream>>>(h1q, alpha, rowptr, col, b1,
                                                     out1q, scl2, ws2, wd2, es, ed);

  // ---- layer 2 (scores fused into aggregate1 epilogue) ----
  alpha_kernel<1><<<NODE_BLOCKS16, 256, 0, stream>>>(es, ed, rowptr, col,
                                                     scl2, alpha);

  const int HALF = NNODES / 2;                       // 25000
  const int AB = (HALF * 64 + 255) / 256;            // 6250 blocks (4 nodes each)
  const int GB = (HALF + 63) / 64;                   // 391 blocks
  agg2in_kernel<<<AB, 256, 0, stream>>>(out1q, alpha, rowptr, col, z, 0, HALF);
  gemm2ln_kernel<<<GB, 256, 0, stream>>>(z, Wt2s, b2, gamma, beta, out, 0, HALF);
  agg2in_kernel<<<AB, 256, 0, stream>>>(out1q, alpha, rowptr, col, z, HALF, NNODES);
  gemm2ln_kernel<<<GB, 256, 0, stream>>>(z, Wt2s, b2, gamma, beta, out, HALF, HALF);
}